// Round 16
// baseline (327.295 us; speedup 1.0000x reference)
//
#include <hip/hip_runtime.h>
#include <hip/hip_fp16.h>

#define HEADS 4

typedef _Float16 v2h __attribute__((ext_vector_type(2)));

// load 4 consecutive halfs (8B aligned) -> float4
__device__ __forceinline__ float4 ldh4(const __half* p) {
    const uint2 u = *(const uint2*)p;
    const float2 a = __half22float2(*(const __half2*)&u.x);
    const float2 b = __half22float2(*(const __half2*)&u.y);
    return make_float4(a.x, a.y, b.x, b.y);
}

__device__ __forceinline__ __half2 habs2_(__half2 x) {
    unsigned u = *reinterpret_cast<unsigned*>(&x) & 0x7FFF7FFFu;
    return *reinterpret_cast<__half2*>(&u);
}

__device__ __forceinline__ float fdot2_(__half2 a, __half2 b, float c) {
    return __builtin_amdgcn_fdot2(*(v2h*)&a, *(v2h*)&b, c, false);
}

// ------- wide GEMM + fused alpha: C[M,BN] = A[M,K] @ B[K,BN] -------
// BM=64, BK=32, 256 threads, micro-tile 4 x MN.
// B PRECONVERTED k-paired fp16. Bank-conflict-free LDS reads:
//   A: one float4 broadcast per k2 (4 ty-groups, distinct banks)
//   B (BN=128): col = j*16+tx  -> 4B stride-1, conflict-free; head=j/2 static
//   B (BN=160): col = tx*10+j  -> stride 40B, 16 distinct banks; head=tx/4
template <int BN, bool AHALF>
__device__ __forceinline__ void gemm_alpha_body(
    const void* __restrict__ Av, const __half2* __restrict__ Bh,
    const float* __restrict__ attq, __half* __restrict__ Cout,
    float* __restrict__ sa, int M, int K, int bid) {
    constexpr int BM = 64, BK = 32;
    constexpr int MN = BN / 16;
    constexpr int C = BN / 4;
    constexpr bool J16 = (BN == 128);   // col = j*16+tx mapping
    __shared__ v2h As2[BK / 2][BM];
    __shared__ v2h Bs2[BK / 2][BN];
    __shared__ float sred[BM][4];
    __shared__ float aq[BN];
    const int m0 = bid * BM;
    const int tid = threadIdx.x;
    const int ty = tid >> 4;   // 0..15
    const int tx = tid & 15;   // 0..15
    for (int i = tid; i < BN; i += 256) aq[i] = attq[i];
    sred[tid >> 2][tid & 3] = 0.f;   // 256 == BM*4
    float acc[4][MN] = {};

    for (int kt = 0; kt < K; kt += BK) {
        // ---- stage A tile (64 rows x 32 k), k-paired half2, transposed ----
        if (!AHALF) {
            const float* A = (const float*)Av;
            #pragma unroll
            for (int it = 0; it < 2; ++it) {
                const int i = tid + 256 * it;    // 512 float4 slots
                const int row = i >> 3;
                const int kc = (i & 7) * 4;
                const int grow = m0 + row;
                float4 v = make_float4(0.f, 0.f, 0.f, 0.f);
                if (grow < M) v = *(const float4*)&A[(size_t)grow * K + kt + kc];
                v2h p0; p0[0] = (_Float16)v.x; p0[1] = (_Float16)v.y;
                v2h p1; p1[0] = (_Float16)v.z; p1[1] = (_Float16)v.w;
                As2[(kc >> 1) + 0][row] = p0;
                As2[(kc >> 1) + 1][row] = p1;
            }
        } else {
            const __half* A = (const __half*)Av;
            #pragma unroll
            for (int it = 0; it < 2; ++it) {
                const int i = tid + 256 * it;
                const int row = i >> 3;
                const int kc = (i & 7) * 4;
                const int grow = m0 + row;
                uint2 u = make_uint2(0u, 0u);
                if (grow < M) u = *(const uint2*)&A[(size_t)grow * K + kt + kc];
                As2[(kc >> 1) + 0][row] = *(v2h*)&u.x;
                As2[(kc >> 1) + 1][row] = *(v2h*)&u.y;
            }
        }
        // ---- stage B tile (32 k x BN): straight 16B copies (preconverted) --
        {
            constexpr int BCH = (BK / 2) * (BN / 4);  // 16B chunks
            for (int i = tid; i < BCH; i += 256) {
                const int k2 = i / (BN / 4);
                const int n4 = (i % (BN / 4)) * 4;
                *(float4*)&Bs2[k2][n4] =
                    *(const float4*)&Bh[(size_t)(kt / 2 + k2) * BN + n4];
            }
        }
        __syncthreads();
        #pragma unroll
        for (int k2 = 0; k2 < BK / 2; ++k2) {
            const float4 af = *(const float4*)&As2[k2][ty * 4];  // broadcast
            const v2h* a_ = (const v2h*)&af;
            v2h b_[MN];
            #pragma unroll
            for (int j = 0; j < MN; ++j)
                b_[j] = Bs2[k2][J16 ? (j * 16 + tx) : (tx * MN + j)];
            #pragma unroll
            for (int i = 0; i < 4; ++i)
                #pragma unroll
                for (int j = 0; j < MN; ++j)
                    acc[i][j] = __builtin_amdgcn_fdot2(a_[i], b_[j], acc[i][j], false);
        }
        __syncthreads();
    }
    // ---- epilogue: fp16 C write + alpha partial reduction ----
    #pragma unroll
    for (int i = 0; i < 4; ++i) {
        const int grow = m0 + ty * 4 + i;
        if (grow < M) {
            if (J16) {
                float hacc[4] = {0.f, 0.f, 0.f, 0.f};
                #pragma unroll
                for (int j = 0; j < MN; ++j) {
                    const int col = j * 16 + tx;
                    Cout[(size_t)grow * BN + col] = (__half)acc[i][j];
                    hacc[j / 2] += acc[i][j] * aq[col];   // static index
                }
                #pragma unroll
                for (int h = 0; h < 4; ++h)
                    atomicAdd(&sred[ty * 4 + i][h], hacc[h]);
            } else {
                const int cbase = tx * MN;
                const int head = cbase / C;
                float part = 0.f;
                #pragma unroll
                for (int j = 0; j < MN; j += 2) {
                    const __half2 h = __floats2half2_rn(acc[i][j], acc[i][j + 1]);
                    *(__half2*)&Cout[(size_t)grow * BN + cbase + j] = h;
                }
                #pragma unroll
                for (int j = 0; j < MN; ++j) part += acc[i][j] * aq[cbase + j];
                atomicAdd(&sred[ty * 4 + i][head], part);
            }
        }
    }
    __syncthreads();
    {
        const int row = m0 + (tid >> 2);
        if (row < M)
            sa[row * 4 + (tid & 3)] =
                1.0f / (1.0f + __expf(-sred[tid >> 2][tid & 3]));
    }
}

// ---- prep: weight fp16 k-paired conversion (blocks < CVB) || dst histogram --
__global__ __launch_bounds__(256)
void prep_k(const float* __restrict__ lin1, const float* __restrict__ lin2,
            __half2* __restrict__ l1h, __half2* __restrict__ l2h,
            const int* __restrict__ dst, int* __restrict__ deg,
            int CVB, int E) {
    if ((int)blockIdx.x < CVB) {
        const int t = blockIdx.x * 256 + threadIdx.x;
        if (t < 128 * 128) {
            const int k2 = t >> 7, nn = t & 127;
            l1h[t] = __floats2half2_rn(lin1[(2 * k2) * 128 + nn],
                                       lin1[(2 * k2 + 1) * 128 + nn]);
        } else {
            const int u = t - 128 * 128;
            if (u < 64 * 160) {
                const int k2 = u / 160, nn = u % 160;
                l2h[u] = __floats2half2_rn(lin2[(2 * k2) * 160 + nn],
                                           lin2[(2 * k2 + 1) * 160 + nn]);
            }
        }
    } else {
        const int e = ((int)blockIdx.x - CVB) * 256 + threadIdx.x;
        if (e < E) atomicAdd(&deg[dst[e]], 1);
    }
}

// ---------------- CSR scan ----------------
__global__ __launch_bounds__(256)
void scan1_k(const int* __restrict__ deg, int* __restrict__ ro,
             int* __restrict__ bsum, int n) {
    __shared__ int s[256];
    int i = blockIdx.x * 256 + threadIdx.x;
    int v = (i < n) ? deg[i] : 0;
    s[threadIdx.x] = v;
    __syncthreads();
    for (int off = 1; off < 256; off <<= 1) {
        int t = (threadIdx.x >= off) ? s[threadIdx.x - off] : 0;
        __syncthreads();
        s[threadIdx.x] += t;
        __syncthreads();
    }
    if (i < n) ro[i] = s[threadIdx.x] - v;
    if (threadIdx.x == 255) bsum[blockIdx.x] = s[255];
}

__global__ __launch_bounds__(256)
void scan23_k(int* __restrict__ ro, int* __restrict__ cur,
              const int* __restrict__ bsum, int n, int E, int nb) {
    __shared__ int s[256];
    int v = ((int)threadIdx.x < nb) ? bsum[threadIdx.x] : 0;
    s[threadIdx.x] = v;
    __syncthreads();
    for (int off = 1; off < 256; off <<= 1) {
        int t = (threadIdx.x >= off) ? s[threadIdx.x - off] : 0;
        __syncthreads();
        s[threadIdx.x] += t;
        __syncthreads();
    }
    const int pref = (blockIdx.x == 0) ? 0 : s[blockIdx.x - 1];  // exclusive
    const int i = blockIdx.x * 256 + threadIdx.x;
    if (i < n) {
        const int r = ro[i] + pref;
        ro[i] = r;
        cur[i] = r;
    }
    if (i == 0) ro[n] = E;
}

// ---- front2: layer-1 GEMM+alpha (blocks < MB) || CSR scatter (rest) ----
__global__ __launch_bounds__(256)
void front2_k(const float* __restrict__ x, const __half2* __restrict__ l1h,
              const float* __restrict__ attq1, __half* __restrict__ xh,
              float* __restrict__ sa, const int* __restrict__ src,
              const int* __restrict__ dst, int* __restrict__ cur,
              int* __restrict__ csr_src, int M, int K, int MB, int E) {
    if ((int)blockIdx.x < MB) {
        gemm_alpha_body<128, false>(x, l1h, attq1, xh, sa, M, K, blockIdx.x);
    } else {
        const int e = ((int)blockIdx.x - MB) * 256 + threadIdx.x;
        if (e < E) {
            const int d = dst[e];
            const int pos = atomicAdd(&cur[d], 1);
            csr_src[pos] = src[e];
        }
    }
}

__global__ __launch_bounds__(256)
void gemm2_k(const __half* __restrict__ acc16, const __half2* __restrict__ l2h,
             const float* __restrict__ attq2, __half* __restrict__ xh,
             float* __restrict__ sa, int M, int K) {
    gemm_alpha_body<160, true>(acc16, l2h, attq2, xh, sa, M, K, blockIdx.x);
}

// ---------------- fused logit+softmax+aggregate+epilogue (fp16 xh) ----------
// 128-thread blocks = TWO independent waves, one node each (beats the
// 16-workgroups/CU cap that limited 64-thread blocks to 50% occupancy).
template <int C, bool CONCAT>
__global__ __launch_bounds__(128)
void fused_edge_k(const int* __restrict__ ro, const int* __restrict__ csr_src,
                  const __half* __restrict__ xh, const float* __restrict__ sa,
                  const float* __restrict__ attv, const float* __restrict__ bias,
                  void* __restrict__ outp, int n) {
    constexpr int HC = 4 * C;
    constexpr int QH = C / 4;        // 4-half chunks per head quarter
    constexpr int CHUNK = 64;        // edges per super-chunk
    constexpr bool DUAL = (C <= 32);
    const int wid = threadIdx.x >> 6;
    const int lane = threadIdx.x & 63;
    const int node = blockIdx.x * 2 + wid;

    __shared__ float wbuf[2][CHUNK * 4];
    __shared__ int sibuf[2][CHUNK];
    __shared__ __half2 avs[HC / 2];
    for (int i = threadIdx.x; i < HC / 2; i += 128)
        avs[i] = __floats2half2_rn(attv[2 * i], attv[2 * i + 1]);
    __syncthreads();
    if (node >= n) return;

    const int s0 = ro[node], s1 = ro[node + 1];

    // logit mapping
    const int e_loc = lane >> 2;
    const int h_l = lane & 3;
    const float sad = sa[node * 4 + h_l];
    const __half2 c505 = __floats2half2_rn(0.505f, 0.505f);
    const __half2 c495 = __floats2half2_rn(0.495f, 0.495f);

    // hoisted dst-row quarter as half2
    __half2 xd[QH * 2];
    {
        const __half* p = &xh[(size_t)node * HC + h_l * C];
        #pragma unroll
        for (int i = 0; i < QH; ++i) {
            const uint2 u = *(const uint2*)&p[i * 4];
            xd[2 * i] = *(const __half2*)&u.x;
            xd[2 * i + 1] = *(const __half2*)&u.y;
        }
    }

    // aggregation mapping
    const int half_ = DUAL ? (lane >> 5) : 0;
    const int q = DUAL ? (lane & 31) : lane;
    const int h_a = (q < C) ? (q / QH) : 0;

    float4 acc = make_float4(0.f, 0.f, 0.f, 0.f);
    float ssum = 0.f;

    for (int base = s0; base < s1; base += CHUNK) {
        const int cnt = min(CHUNK, s1 - base);
        const int npass = (cnt + 15) >> 4;
        // ---- logit passes: 16 edges x 4 heads per pass, packed fp16 ----
        for (int p = 0; p < npass; ++p) {
            const int eidx = p * 16 + e_loc;
            const int j = base + eidx;
            float w = 0.f;
            int si = 0;
            if (j < s1) {
                si = csr_src[j];
                const float sas = sa[si * 4 + h_l];
                const float wa = 1.0f - fabsf(sad - sas);
                const __half* xs = &xh[(size_t)si * HC + h_l * C];
                float wb = 0.f;
                #pragma unroll
                for (int i = 0; i < QH; ++i) {
                    const uint2 u = *(const uint2*)&xs[i * 4];
                    const __half2 a0 = *(const __half2*)&u.x;
                    const __half2 a1 = *(const __half2*)&u.y;
                    const __half2 t0 = __hadd2(a0, xd[2 * i]);
                    const __half2 t1 = __hadd2(a1, xd[2 * i + 1]);
                    const __half2 l0 = __hfma2(t0, c505, __hmul2(habs2_(t0), c495));
                    const __half2 l1 = __hfma2(t1, c505, __hmul2(habs2_(t1), c495));
                    wb = fdot2_(l0, avs[h_l * QH * 2 + 2 * i], wb);
                    wb = fdot2_(l1, avs[h_l * QH * 2 + 2 * i + 1], wb);
                }
                w = __expf(fminf(wa * wb, 60.f));  // inf-guard only
                ssum += w;
            }
            wbuf[wid][eidx * 4 + h_l] = w;
            if (h_l == 0) sibuf[wid][eidx] = si;
        }
        // ---- aggregation: padded slots carry w=0/si=0, no guards ----
        const int padded = npass << 4;
        if (q < C) {
            if (DUAL) {
                for (int i = 0; i < padded; i += 8) {
                    const int e0 = i + half_, e1 = i + half_ + 2;
                    const int e2 = i + half_ + 4, e3 = i + half_ + 6;
                    const int i0 = sibuf[wid][e0], i1 = sibuf[wid][e1];
                    const int i2 = sibuf[wid][e2], i3 = sibuf[wid][e3];
                    const float w0 = wbuf[wid][e0 * 4 + h_a];
                    const float w1 = wbuf[wid][e1 * 4 + h_a];
                    const float w2 = wbuf[wid][e2 * 4 + h_a];
                    const float w3 = wbuf[wid][e3 * 4 + h_a];
                    const float4 v0 = ldh4(&xh[(size_t)i0 * HC + q * 4]);
                    const float4 v1 = ldh4(&xh[(size_t)i1 * HC + q * 4]);
                    const float4 v2 = ldh4(&xh[(size_t)i2 * HC + q * 4]);
                    const float4 v3 = ldh4(&xh[(size_t)i3 * HC + q * 4]);
                    acc.x += w0 * v0.x + w1 * v1.x + w2 * v2.x + w3 * v3.x;
                    acc.y += w0 * v0.y + w1 * v1.y + w2 * v2.y + w3 * v3.y;
                    acc.z += w0 * v0.z + w1 * v1.z + w2 * v2.z + w3 * v3.z;
                    acc.w += w0 * v0.w + w1 * v1.w + w2 * v2.w + w3 * v3.w;
                }
            } else {
                for (int i = 0; i < padded; i += 4) {
                    const int i0 = sibuf[wid][i],     i1 = sibuf[wid][i + 1];
                    const int i2 = sibuf[wid][i + 2], i3 = sibuf[wid][i + 3];
                    const float w0 = wbuf[wid][(i + 0) * 4 + h_a];
                    const float w1 = wbuf[wid][(i + 1) * 4 + h_a];
                    const float w2 = wbuf[wid][(i + 2) * 4 + h_a];
                    const float w3 = wbuf[wid][(i + 3) * 4 + h_a];
                    const float4 v0 = ldh4(&xh[(size_t)i0 * HC + q * 4]);
                    const float4 v1 = ldh4(&xh[(size_t)i1 * HC + q * 4]);
                    const float4 v2 = ldh4(&xh[(size_t)i2 * HC + q * 4]);
                    const float4 v3 = ldh4(&xh[(size_t)i3 * HC + q * 4]);
                    acc.x += w0 * v0.x + w1 * v1.x + w2 * v2.x + w3 * v3.x;
                    acc.y += w0 * v0.y + w1 * v1.y + w2 * v2.y + w3 * v3.y;
                    acc.z += w0 * v0.z + w1 * v1.z + w2 * v2.z + w3 * v3.z;
                    acc.w += w0 * v0.w + w1 * v1.w + w2 * v2.w + w3 * v3.w;
                }
            }
        }
    }

    // combine dual halves
    if (DUAL) {
        acc.x += __shfl_xor(acc.x, 32, 64);
        acc.y += __shfl_xor(acc.y, 32, 64);
        acc.z += __shfl_xor(acc.z, 32, 64);
        acc.w += __shfl_xor(acc.w, 32, 64);
    }

    // per-head sum of weights: reduce across lanes sharing (lane & 3)
    #pragma unroll
    for (int off = 4; off < 64; off <<= 1) ssum += __shfl_xor(ssum, off, 64);
    const float stot = __shfl(ssum, h_a, 64);
    const float inv = 1.0f / (stot + 1e-20f);
    acc.x *= inv; acc.y *= inv; acc.z *= inv; acc.w *= inv;

    if (CONCAT) {
        if (q < C && half_ == 0) {
            const float4 b = ((const float4*)bias)[q];
            float4 v = make_float4(acc.x + b.x, acc.y + b.y, acc.z + b.z, acc.w + b.w);
            v.x = v.x > 0.f ? v.x : __expf(v.x) - 1.0f;
            v.y = v.y > 0.f ? v.y : __expf(v.y) - 1.0f;
            v.z = v.z > 0.f ? v.z : __expf(v.z) - 1.0f;
            v.w = v.w > 0.f ? v.w : __expf(v.w) - 1.0f;
            __half* o16 = (__half*)outp;
            const __half2 h01 = __floats2half2_rn(v.x, v.y);
            const __half2 h23 = __floats2half2_rn(v.z, v.w);
            uint2 u;
            u.x = *(const unsigned*)&h01;
            u.y = *(const unsigned*)&h23;
            *(uint2*)&o16[(size_t)node * HC + q * 4] = u;
        }
    } else {
        // head-mean via shuffles
        const int qq = (q < QH) ? q : 0;
        const float x1 = __shfl(acc.x, qq + QH, 64);
        const float y1 = __shfl(acc.y, qq + QH, 64);
        const float z1 = __shfl(acc.z, qq + QH, 64);
        const float w1 = __shfl(acc.w, qq + QH, 64);
        const float x2 = __shfl(acc.x, qq + 2 * QH, 64);
        const float y2 = __shfl(acc.y, qq + 2 * QH, 64);
        const float z2 = __shfl(acc.z, qq + 2 * QH, 64);
        const float w2 = __shfl(acc.w, qq + 2 * QH, 64);
        const float x3 = __shfl(acc.x, qq + 3 * QH, 64);
        const float y3 = __shfl(acc.y, qq + 3 * QH, 64);
        const float z3 = __shfl(acc.z, qq + 3 * QH, 64);
        const float w3 = __shfl(acc.w, qq + 3 * QH, 64);
        if (q < QH && half_ == 0) {
            float* of = (float*)outp;
            const float4 b = ((const float4*)bias)[q];
            float4 v;
            v.x = 0.25f * (acc.x + x1 + x2 + x3) + b.x;
            v.y = 0.25f * (acc.y + y1 + y2 + y3) + b.y;
            v.z = 0.25f * (acc.z + z1 + z2 + z3) + b.z;
            v.w = 0.25f * (acc.w + w1 + w2 + w3) + b.w;
            *(float4*)&of[(size_t)node * C + q * 4] = v;
        }
    }
}

extern "C" void kernel_launch(void* const* d_in, const int* in_sizes, int n_in,
                              void* d_out, int out_size, void* d_ws, size_t ws_size,
                              hipStream_t stream) {
    const float* x      = (const float*)d_in[0];
    const int*   src    = (const int*)d_in[1];
    const int*   dst    = (const int*)d_in[2];
    const float* lin1   = (const float*)d_in[3];
    const float* att_q1 = (const float*)d_in[4];
    const float* att_v1 = (const float*)d_in[5];
    const float* bias1  = (const float*)d_in[6];
    const float* lin2   = (const float*)d_in[7];
    const float* att_q2 = (const float*)d_in[8];
    const float* att_v2 = (const float*)d_in[9];
    const float* bias2  = (const float*)d_in[10];
    float* outp = (float*)d_out;

    const int n = in_sizes[0] / 256;
    const int E = in_sizes[1];
    const int nh = n * HEADS;
    const int NB = (n + 255) / 256;

    char* wsb = (char*)d_ws;
    size_t o = 0;
    __half* xh     = (__half*)(wsb + o); o += (size_t)n * 160 * 2;
    __half* acc16  = (__half*)(wsb + o); o += (size_t)n * 128 * 2;
    float* sa      = (float*)(wsb + o); o += (size_t)nh * 4;
    int* csr_src   = (int*)(wsb + o); o += (size_t)E * 4;
    int* deg       = (int*)(wsb + o); o += (size_t)n * 4;
    int* ro        = (int*)(wsb + o); o += (size_t)(n + 1) * 4;
    int* cur       = (int*)(wsb + o); o += (size_t)n * 4;
    int* bsum      = (int*)(wsb + o); o += 256 * 4;
    __half2* l1h   = (__half2*)(wsb + o); o += (size_t)128 * 128 * 4;
    __half2* l2h   = (__half2*)(wsb + o); o += (size_t)64 * 160 * 4;

    dim3 blk(256);
    const int EG = (E + 255) / 256;
    const int MB = (n + 63) / 64;
    const int CVB = (128 * 128 + 64 * 160 + 255) / 256;

    // ---- prep: weight conversion || dst histogram ----
    hipMemsetAsync(deg, 0, (size_t)n * 4, stream);
    prep_k<<<CVB + EG, blk, 0, stream>>>(lin1, lin2, l1h, l2h, dst, deg, CVB, E);
    // ---- CSR scan (2 kernels) ----
    scan1_k<<<NB, blk, 0, stream>>>(deg, ro, bsum, n);
    scan23_k<<<NB, blk, 0, stream>>>(ro, cur, bsum, n, E, NB);
    // ---- front2: layer-1 GEMM+alpha || CSR scatter ----
    front2_k<<<MB + EG, blk, 0, stream>>>(x, l1h, att_q1, xh, sa, src, dst,
                                          cur, csr_src, n, 256, MB, E);
    // ---- layer 1 edge phase (2 waves / block, 1 node / wave) ----
    fused_edge_k<32, true><<<(n + 1) / 2, dim3(128), 0, stream>>>(ro, csr_src, xh, sa, att_v1, bias1, acc16, n);
    // ---- layer 2 ----
    gemm2_k<<<MB, blk, 0, stream>>>(acc16, l2h, att_q2, xh, sa, n, 128);
    fused_edge_k<40, false><<<(n + 1) / 2, dim3(128), 0, stream>>>(ro, csr_src, xh, sa, att_v2, bias2, outp, n);
}

// Round 17
// 321.051 us; speedup vs baseline: 1.0195x; 1.0195x over previous
//
#include <hip/hip_runtime.h>
#include <hip/hip_fp16.h>

#define HEADS 4

typedef _Float16 v2h __attribute__((ext_vector_type(2)));

// load 4 consecutive halfs (8B aligned) -> float4
__device__ __forceinline__ float4 ldh4(const __half* p) {
    const uint2 u = *(const uint2*)p;
    const float2 a = __half22float2(*(const __half2*)&u.x);
    const float2 b = __half22float2(*(const __half2*)&u.y);
    return make_float4(a.x, a.y, b.x, b.y);
}

__device__ __forceinline__ __half2 habs2_(__half2 x) {
    unsigned u = *reinterpret_cast<unsigned*>(&x) & 0x7FFF7FFFu;
    return *reinterpret_cast<__half2*>(&u);
}

__device__ __forceinline__ float fdot2_(__half2 a, __half2 b, float c) {
    return __builtin_amdgcn_fdot2(*(v2h*)&a, *(v2h*)&b, c, false);
}

// ------- wide GEMM + fused alpha: C[M,BN] = A[M,K] @ B[K,BN] -------
// BM=64, BK=32, 256 threads, micro-tile 4 x (BN/16).  (R15 version)
template <int BN, bool AHALF>
__device__ __forceinline__ void gemm_alpha_body(
    const void* __restrict__ Av, const __half2* __restrict__ Bh,
    const float* __restrict__ attq, __half* __restrict__ Cout,
    float* __restrict__ sa, int M, int K, int bid) {
    constexpr int BM = 64, BK = 32;
    constexpr int MN = BN / 16;
    constexpr int C = BN / 4;
    __shared__ v2h As2[BK / 2][BM];
    __shared__ v2h Bs2[BK / 2][BN];
    __shared__ float sred[BM][4];
    __shared__ float aq[BN];
    const int m0 = bid * BM;
    const int tid = threadIdx.x;
    const int ty = tid >> 4;   // 0..15
    const int tx = tid & 15;   // 0..15
    for (int i = tid; i < BN; i += 256) aq[i] = attq[i];
    sred[tid >> 2][tid & 3] = 0.f;   // 256 == BM*4
    float acc[4][MN] = {};

    for (int kt = 0; kt < K; kt += BK) {
        // ---- stage A tile (64 rows x 32 k), k-paired half2, transposed ----
        if (!AHALF) {
            const float* A = (const float*)Av;
            #pragma unroll
            for (int it = 0; it < 2; ++it) {
                const int i = tid + 256 * it;    // 512 float4 slots
                const int row = i >> 3;
                const int kc = (i & 7) * 4;
                const int grow = m0 + row;
                float4 v = make_float4(0.f, 0.f, 0.f, 0.f);
                if (grow < M) v = *(const float4*)&A[(size_t)grow * K + kt + kc];
                v2h p0; p0[0] = (_Float16)v.x; p0[1] = (_Float16)v.y;
                v2h p1; p1[0] = (_Float16)v.z; p1[1] = (_Float16)v.w;
                As2[(kc >> 1) + 0][row] = p0;
                As2[(kc >> 1) + 1][row] = p1;
            }
        } else {
            const __half* A = (const __half*)Av;
            #pragma unroll
            for (int it = 0; it < 2; ++it) {
                const int i = tid + 256 * it;
                const int row = i >> 3;
                const int kc = (i & 7) * 4;
                const int grow = m0 + row;
                uint2 u = make_uint2(0u, 0u);
                if (grow < M) u = *(const uint2*)&A[(size_t)grow * K + kt + kc];
                As2[(kc >> 1) + 0][row] = *(v2h*)&u.x;
                As2[(kc >> 1) + 1][row] = *(v2h*)&u.y;
            }
        }
        // ---- stage B tile (32 k x BN): straight 16B copies (preconverted) --
        {
            constexpr int BCH = (BK / 2) * (BN / 4);  // 16B chunks
            for (int i = tid; i < BCH; i += 256) {
                const int k2 = i / (BN / 4);
                const int n4 = (i % (BN / 4)) * 4;
                *(float4*)&Bs2[k2][n4] =
                    *(const float4*)&Bh[(size_t)(kt / 2 + k2) * BN + n4];
            }
        }
        __syncthreads();
        #pragma unroll
        for (int k2 = 0; k2 < BK / 2; ++k2) {
            v2h a_[4], b_[MN];
            #pragma unroll
            for (int i = 0; i < 4; ++i) a_[i] = As2[k2][ty * 4 + i];
            #pragma unroll
            for (int j = 0; j < MN; ++j) b_[j] = Bs2[k2][tx * MN + j];
            #pragma unroll
            for (int i = 0; i < 4; ++i)
                #pragma unroll
                for (int j = 0; j < MN; ++j)
                    acc[i][j] = __builtin_amdgcn_fdot2(a_[i], b_[j], acc[i][j], false);
        }
        __syncthreads();
    }
    // ---- epilogue: fp16 C write + alpha partial reduction ----
    const int cbase = tx * MN;
    const int head = cbase / C;      // MN cols always within one head
    #pragma unroll
    for (int i = 0; i < 4; ++i) {
        const int grow = m0 + ty * 4 + i;
        if (grow < M) {
            #pragma unroll
            for (int j = 0; j < MN; j += 2) {
                const __half2 h = __floats2half2_rn(acc[i][j], acc[i][j + 1]);
                *(__half2*)&Cout[(size_t)grow * BN + cbase + j] = h;
            }
            float part = 0.f;
            #pragma unroll
            for (int j = 0; j < MN; ++j) part += acc[i][j] * aq[cbase + j];
            atomicAdd(&sred[ty * 4 + i][head], part);
        }
    }
    __syncthreads();
    {
        const int row = m0 + (tid >> 2);
        if (row < M)
            sa[row * 4 + (tid & 3)] =
                1.0f / (1.0f + __expf(-sred[tid >> 2][tid & 3]));
    }
}

// ---- prep: weight fp16 k-paired conversion (blocks < CVB) || dst histogram --
__global__ __launch_bounds__(256)
void prep_k(const float* __restrict__ lin1, const float* __restrict__ lin2,
            __half2* __restrict__ l1h, __half2* __restrict__ l2h,
            const int* __restrict__ dst, int* __restrict__ deg,
            int CVB, int E) {
    if ((int)blockIdx.x < CVB) {
        const int t = blockIdx.x * 256 + threadIdx.x;
        if (t < 128 * 128) {
            const int k2 = t >> 7, nn = t & 127;
            l1h[t] = __floats2half2_rn(lin1[(2 * k2) * 128 + nn],
                                       lin1[(2 * k2 + 1) * 128 + nn]);
        } else {
            const int u = t - 128 * 128;
            if (u < 64 * 160) {
                const int k2 = u / 160, nn = u % 160;
                l2h[u] = __floats2half2_rn(lin2[(2 * k2) * 160 + nn],
                                           lin2[(2 * k2 + 1) * 160 + nn]);
            }
        }
    } else {
        const int e = ((int)blockIdx.x - CVB) * 256 + threadIdx.x;
        if (e < E) atomicAdd(&deg[dst[e]], 1);
    }
}

// ---------------- CSR scan ----------------
__global__ __launch_bounds__(256)
void scan1_k(const int* __restrict__ deg, int* __restrict__ ro,
             int* __restrict__ bsum, int n) {
    __shared__ int s[256];
    int i = blockIdx.x * 256 + threadIdx.x;
    int v = (i < n) ? deg[i] : 0;
    s[threadIdx.x] = v;
    __syncthreads();
    for (int off = 1; off < 256; off <<= 1) {
        int t = (threadIdx.x >= off) ? s[threadIdx.x - off] : 0;
        __syncthreads();
        s[threadIdx.x] += t;
        __syncthreads();
    }
    if (i < n) ro[i] = s[threadIdx.x] - v;
    if (threadIdx.x == 255) bsum[blockIdx.x] = s[255];
}

__global__ __launch_bounds__(256)
void scan23_k(int* __restrict__ ro, int* __restrict__ cur,
              const int* __restrict__ bsum, int n, int E, int nb) {
    __shared__ int s[256];
    int v = ((int)threadIdx.x < nb) ? bsum[threadIdx.x] : 0;
    s[threadIdx.x] = v;
    __syncthreads();
    for (int off = 1; off < 256; off <<= 1) {
        int t = (threadIdx.x >= off) ? s[threadIdx.x - off] : 0;
        __syncthreads();
        s[threadIdx.x] += t;
        __syncthreads();
    }
    const int pref = (blockIdx.x == 0) ? 0 : s[blockIdx.x - 1];  // exclusive
    const int i = blockIdx.x * 256 + threadIdx.x;
    if (i < n) {
        const int r = ro[i] + pref;
        ro[i] = r;
        cur[i] = r;
    }
    if (i == 0) ro[n] = E;
}

// ---- front2: layer-1 GEMM+alpha (blocks < MB) || CSR scatter (rest) ----
__global__ __launch_bounds__(256)
void front2_k(const float* __restrict__ x, const __half2* __restrict__ l1h,
              const float* __restrict__ attq1, __half* __restrict__ xh,
              float* __restrict__ sa, const int* __restrict__ src,
              const int* __restrict__ dst, int* __restrict__ cur,
              int* __restrict__ csr_src, int M, int K, int MB, int E) {
    if ((int)blockIdx.x < MB) {
        gemm_alpha_body<128, false>(x, l1h, attq1, xh, sa, M, K, blockIdx.x);
    } else {
        const int e = ((int)blockIdx.x - MB) * 256 + threadIdx.x;
        if (e < E) {
            const int d = dst[e];
            const int pos = atomicAdd(&cur[d], 1);
            csr_src[pos] = src[e];
        }
    }
}

__global__ __launch_bounds__(256)
void gemm2_k(const __half* __restrict__ acc16, const __half2* __restrict__ l2h,
             const float* __restrict__ attq2, __half* __restrict__ xh,
             float* __restrict__ sa, int M, int K) {
    gemm_alpha_body<160, true>(acc16, l2h, attq2, xh, sa, M, K, blockIdx.x);
}

// ---------------- fused logit+softmax+aggregate+epilogue (fp16 xh) ----------
// 128-thread blocks = TWO fully independent waves (one node each), NO BARRIER:
// each wave redundantly writes the whole avs LDS copy (identical values), so
// no cross-wave synchronization exists. Beats the 16-WG/CU cap (32 waves/CU).
template <int C, bool CONCAT>
__global__ __launch_bounds__(128)
void fused_edge_k(const int* __restrict__ ro, const int* __restrict__ csr_src,
                  const __half* __restrict__ xh, const float* __restrict__ sa,
                  const float* __restrict__ attv, const float* __restrict__ bias,
                  void* __restrict__ outp, int n) {
    constexpr int HC = 4 * C;
    constexpr int QH = C / 4;        // 4-half chunks per head quarter
    constexpr int CHUNK = 64;        // edges per super-chunk
    constexpr bool DUAL = (C <= 32);
    const int wid = threadIdx.x >> 6;
    const int lane = threadIdx.x & 63;
    const int node = blockIdx.x * 2 + wid;

    __shared__ float wbuf[2][CHUNK * 4];
    __shared__ int sibuf[2][CHUNK];
    __shared__ __half2 avs[HC / 2];
    // per-wave redundant init (same values) -> no barrier needed
    for (int i = lane; i < HC / 2; i += 64)
        avs[i] = __floats2half2_rn(attv[2 * i], attv[2 * i + 1]);
    if (node >= n) return;

    const int s0 = ro[node], s1 = ro[node + 1];

    // logit mapping
    const int e_loc = lane >> 2;
    const int h_l = lane & 3;
    const float sad = sa[node * 4 + h_l];
    const __half2 c505 = __floats2half2_rn(0.505f, 0.505f);
    const __half2 c495 = __floats2half2_rn(0.495f, 0.495f);

    // hoisted dst-row quarter as half2
    __half2 xd[QH * 2];
    {
        const __half* p = &xh[(size_t)node * HC + h_l * C];
        #pragma unroll
        for (int i = 0; i < QH; ++i) {
            const uint2 u = *(const uint2*)&p[i * 4];
            xd[2 * i] = *(const __half2*)&u.x;
            xd[2 * i + 1] = *(const __half2*)&u.y;
        }
    }

    // aggregation mapping
    const int half_ = DUAL ? (lane >> 5) : 0;
    const int q = DUAL ? (lane & 31) : lane;
    const int h_a = (q < C) ? (q / QH) : 0;

    float4 acc = make_float4(0.f, 0.f, 0.f, 0.f);
    float ssum = 0.f;

    for (int base = s0; base < s1; base += CHUNK) {
        const int cnt = min(CHUNK, s1 - base);
        const int npass = (cnt + 15) >> 4;
        // ---- logit passes: 16 edges x 4 heads per pass, packed fp16 ----
        for (int p = 0; p < npass; ++p) {
            const int eidx = p * 16 + e_loc;
            const int j = base + eidx;
            float w = 0.f;
            int si = 0;
            if (j < s1) {
                si = csr_src[j];
                const float sas = sa[si * 4 + h_l];
                const float wa = 1.0f - fabsf(sad - sas);
                const __half* xs = &xh[(size_t)si * HC + h_l * C];
                float wb = 0.f;
                #pragma unroll
                for (int i = 0; i < QH; ++i) {
                    const uint2 u = *(const uint2*)&xs[i * 4];
                    const __half2 a0 = *(const __half2*)&u.x;
                    const __half2 a1 = *(const __half2*)&u.y;
                    const __half2 t0 = __hadd2(a0, xd[2 * i]);
                    const __half2 t1 = __hadd2(a1, xd[2 * i + 1]);
                    const __half2 l0 = __hfma2(t0, c505, __hmul2(habs2_(t0), c495));
                    const __half2 l1 = __hfma2(t1, c505, __hmul2(habs2_(t1), c495));
                    wb = fdot2_(l0, avs[h_l * QH * 2 + 2 * i], wb);
                    wb = fdot2_(l1, avs[h_l * QH * 2 + 2 * i + 1], wb);
                }
                w = __expf(fminf(wa * wb, 60.f));  // inf-guard only
                ssum += w;
            }
            wbuf[wid][eidx * 4 + h_l] = w;
            if (h_l == 0) sibuf[wid][eidx] = si;
        }
        // ---- aggregation: padded slots carry w=0/si=0, no guards ----
        const int padded = npass << 4;
        if (q < C) {
            if (DUAL) {
                for (int i = 0; i < padded; i += 8) {
                    const int e0 = i + half_, e1 = i + half_ + 2;
                    const int e2 = i + half_ + 4, e3 = i + half_ + 6;
                    const int i0 = sibuf[wid][e0], i1 = sibuf[wid][e1];
                    const int i2 = sibuf[wid][e2], i3 = sibuf[wid][e3];
                    const float w0 = wbuf[wid][e0 * 4 + h_a];
                    const float w1 = wbuf[wid][e1 * 4 + h_a];
                    const float w2 = wbuf[wid][e2 * 4 + h_a];
                    const float w3 = wbuf[wid][e3 * 4 + h_a];
                    const float4 v0 = ldh4(&xh[(size_t)i0 * HC + q * 4]);
                    const float4 v1 = ldh4(&xh[(size_t)i1 * HC + q * 4]);
                    const float4 v2 = ldh4(&xh[(size_t)i2 * HC + q * 4]);
                    const float4 v3 = ldh4(&xh[(size_t)i3 * HC + q * 4]);
                    acc.x += w0 * v0.x + w1 * v1.x + w2 * v2.x + w3 * v3.x;
                    acc.y += w0 * v0.y + w1 * v1.y + w2 * v2.y + w3 * v3.y;
                    acc.z += w0 * v0.z + w1 * v1.z + w2 * v2.z + w3 * v3.z;
                    acc.w += w0 * v0.w + w1 * v1.w + w2 * v2.w + w3 * v3.w;
                }
            } else {
                for (int i = 0; i < padded; i += 4) {
                    const int i0 = sibuf[wid][i],     i1 = sibuf[wid][i + 1];
                    const int i2 = sibuf[wid][i + 2], i3 = sibuf[wid][i + 3];
                    const float w0 = wbuf[wid][(i + 0) * 4 + h_a];
                    const float w1 = wbuf[wid][(i + 1) * 4 + h_a];
                    const float w2 = wbuf[wid][(i + 2) * 4 + h_a];
                    const float w3 = wbuf[wid][(i + 3) * 4 + h_a];
                    const float4 v0 = ldh4(&xh[(size_t)i0 * HC + q * 4]);
                    const float4 v1 = ldh4(&xh[(size_t)i1 * HC + q * 4]);
                    const float4 v2 = ldh4(&xh[(size_t)i2 * HC + q * 4]);
                    const float4 v3 = ldh4(&xh[(size_t)i3 * HC + q * 4]);
                    acc.x += w0 * v0.x + w1 * v1.x + w2 * v2.x + w3 * v3.x;
                    acc.y += w0 * v0.y + w1 * v1.y + w2 * v2.y + w3 * v3.y;
                    acc.z += w0 * v0.z + w1 * v1.z + w2 * v2.z + w3 * v3.z;
                    acc.w += w0 * v0.w + w1 * v1.w + w2 * v2.w + w3 * v3.w;
                }
            }
        }
    }

    // combine dual halves
    if (DUAL) {
        acc.x += __shfl_xor(acc.x, 32, 64);
        acc.y += __shfl_xor(acc.y, 32, 64);
        acc.z += __shfl_xor(acc.z, 32, 64);
        acc.w += __shfl_xor(acc.w, 32, 64);
    }

    // per-head sum of weights: reduce across lanes sharing (lane & 3)
    #pragma unroll
    for (int off = 4; off < 64; off <<= 1) ssum += __shfl_xor(ssum, off, 64);
    const float stot = __shfl(ssum, h_a, 64);
    const float inv = 1.0f / (stot + 1e-20f);
    acc.x *= inv; acc.y *= inv; acc.z *= inv; acc.w *= inv;

    if (CONCAT) {
        if (q < C && half_ == 0) {
            const float4 b = ((const float4*)bias)[q];
            float4 v = make_float4(acc.x + b.x, acc.y + b.y, acc.z + b.z, acc.w + b.w);
            v.x = v.x > 0.f ? v.x : __expf(v.x) - 1.0f;
            v.y = v.y > 0.f ? v.y : __expf(v.y) - 1.0f;
            v.z = v.z > 0.f ? v.z : __expf(v.z) - 1.0f;
            v.w = v.w > 0.f ? v.w : __expf(v.w) - 1.0f;
            __half* o16 = (__half*)outp;
            const __half2 h01 = __floats2half2_rn(v.x, v.y);
            const __half2 h23 = __floats2half2_rn(v.z, v.w);
            uint2 u;
            u.x = *(const unsigned*)&h01;
            u.y = *(const unsigned*)&h23;
            *(uint2*)&o16[(size_t)node * HC + q * 4] = u;
        }
    } else {
        // head-mean via shuffles
        const int qq = (q < QH) ? q : 0;
        const float x1 = __shfl(acc.x, qq + QH, 64);
        const float y1 = __shfl(acc.y, qq + QH, 64);
        const float z1 = __shfl(acc.z, qq + QH, 64);
        const float w1 = __shfl(acc.w, qq + QH, 64);
        const float x2 = __shfl(acc.x, qq + 2 * QH, 64);
        const float y2 = __shfl(acc.y, qq + 2 * QH, 64);
        const float z2 = __shfl(acc.z, qq + 2 * QH, 64);
        const float w2 = __shfl(acc.w, qq + 2 * QH, 64);
        const float x3 = __shfl(acc.x, qq + 3 * QH, 64);
        const float y3 = __shfl(acc.y, qq + 3 * QH, 64);
        const float z3 = __shfl(acc.z, qq + 3 * QH, 64);
        const float w3 = __shfl(acc.w, qq + 3 * QH, 64);
        if (q < QH && half_ == 0) {
            float* of = (float*)outp;
            const float4 b = ((const float4*)bias)[q];
            float4 v;
            v.x = 0.25f * (acc.x + x1 + x2 + x3) + b.x;
            v.y = 0.25f * (acc.y + y1 + y2 + y3) + b.y;
            v.z = 0.25f * (acc.z + z1 + z2 + z3) + b.z;
            v.w = 0.25f * (acc.w + w1 + w2 + w3) + b.w;
            *(float4*)&of[(size_t)node * C + q * 4] = v;
        }
    }
}

extern "C" void kernel_launch(void* const* d_in, const int* in_sizes, int n_in,
                              void* d_out, int out_size, void* d_ws, size_t ws_size,
                              hipStream_t stream) {
    const float* x      = (const float*)d_in[0];
    const int*   src    = (const int*)d_in[1];
    const int*   dst    = (const int*)d_in[2];
    const float* lin1   = (const float*)d_in[3];
    const float* att_q1 = (const float*)d_in[4];
    const float* att_v1 = (const float*)d_in[5];
    const float* bias1  = (const float*)d_in[6];
    const float* lin2   = (const float*)d_in[7];
    const float* att_q2 = (const float*)d_in[8];
    const float* att_v2 = (const float*)d_in[9];
    const float* bias2  = (const float*)d_in[10];
    float* outp = (float*)d_out;

    const int n = in_sizes[0] / 256;
    const int E = in_sizes[1];
    const int nh = n * HEADS;
    const int NB = (n + 255) / 256;

    char* wsb = (char*)d_ws;
    size_t o = 0;
    __half* xh     = (__half*)(wsb + o); o += (size_t)n * 160 * 2;
    __half* acc16  = (__half*)(wsb + o); o += (size_t)n * 128 * 2;
    float* sa      = (float*)(wsb + o); o += (size_t)nh * 4;
    int* csr_src   = (int*)(wsb + o); o += (size_t)E * 4;
    int* deg       = (int*)(wsb + o); o += (size_t)n * 4;
    int* ro        = (int*)(wsb + o); o += (size_t)(n + 1) * 4;
    int* cur       = (int*)(wsb + o); o += (size_t)n * 4;
    int* bsum      = (int*)(wsb + o); o += 256 * 4;
    __half2* l1h   = (__half2*)(wsb + o); o += (size_t)128 * 128 * 4;
    __half2* l2h   = (__half2*)(wsb + o); o += (size_t)64 * 160 * 4;

    dim3 blk(256);
    const int EG = (E + 255) / 256;
    const int MB = (n + 63) / 64;
    const int CVB = (128 * 128 + 64 * 160 + 255) / 256;

    // ---- prep: weight conversion || dst histogram ----
    hipMemsetAsync(deg, 0, (size_t)n * 4, stream);
    prep_k<<<CVB + EG, blk, 0, stream>>>(lin1, lin2, l1h, l2h, dst, deg, CVB, E);
    // ---- CSR scan (2 kernels) ----
    scan1_k<<<NB, blk, 0, stream>>>(deg, ro, bsum, n);
    scan23_k<<<NB, blk, 0, stream>>>(ro, cur, bsum, n, E, NB);
    // ---- front2: layer-1 GEMM+alpha || CSR scatter ----
    front2_k<<<MB + EG, blk, 0, stream>>>(x, l1h, att_q1, xh, sa, src, dst,
                                          cur, csr_src, n, 256, MB, E);
    // ---- layer 1 edge phase (2 independent waves / block) ----
    fused_edge_k<32, true><<<(n + 1) / 2, dim3(128), 0, stream>>>(ro, csr_src, xh, sa, att_v1, bias1, acc16, n);
    // ---- layer 2 ----
    gemm2_k<<<MB, blk, 0, stream>>>(acc16, l2h, att_q2, xh, sa, n, 128);
    fused_edge_k<40, false><<<(n + 1) / 2, dim3(128), 0, stream>>>(ro, csr_src, xh, sa, att_v2, bias2, outp, n);
}

// Round 18
// 302.920 us; speedup vs baseline: 1.0805x; 1.0599x over previous
//
#include <hip/hip_runtime.h>
#include <hip/hip_fp16.h>

#define HEADS 4

typedef _Float16 v2h __attribute__((ext_vector_type(2)));

// load 4 consecutive halfs (8B aligned) -> float4
__device__ __forceinline__ float4 ldh4(const __half* p) {
    const uint2 u = *(const uint2*)p;
    const float2 a = __half22float2(*(const __half2*)&u.x);
    const float2 b = __half22float2(*(const __half2*)&u.y);
    return make_float4(a.x, a.y, b.x, b.y);
}

__device__ __forceinline__ __half2 habs2_(__half2 x) {
    unsigned u = *reinterpret_cast<unsigned*>(&x) & 0x7FFF7FFFu;
    return *reinterpret_cast<__half2*>(&u);
}

__device__ __forceinline__ float fdot2_(__half2 a, __half2 b, float c) {
    return __builtin_amdgcn_fdot2(*(v2h*)&a, *(v2h*)&b, c, false);
}

// ------- wide GEMM + fused alpha: C[M,BN] = A[M,K] @ B[K,BN] -------
// BM=64, BK=32, 256 threads, micro-tile 4 x (BN/16). R15 layout; inner-loop
// LDS reads widened to float4 where 16B-aligned (bit-identical values).
template <int BN, bool AHALF>
__device__ __forceinline__ void gemm_alpha_body(
    const void* __restrict__ Av, const __half2* __restrict__ Bh,
    const float* __restrict__ attq, __half* __restrict__ Cout,
    float* __restrict__ sa, int M, int K, int bid) {
    constexpr int BM = 64, BK = 32;
    constexpr int MN = BN / 16;
    constexpr int C = BN / 4;
    __shared__ v2h As2[BK / 2][BM];
    __shared__ v2h Bs2[BK / 2][BN];
    __shared__ float sred[BM][4];
    __shared__ float aq[BN];
    const int m0 = bid * BM;
    const int tid = threadIdx.x;
    const int ty = tid >> 4;   // 0..15
    const int tx = tid & 15;   // 0..15
    for (int i = tid; i < BN; i += 256) aq[i] = attq[i];
    sred[tid >> 2][tid & 3] = 0.f;   // 256 == BM*4
    float acc[4][MN] = {};

    for (int kt = 0; kt < K; kt += BK) {
        // ---- stage A tile (64 rows x 32 k), k-paired half2, transposed ----
        if (!AHALF) {
            const float* A = (const float*)Av;
            #pragma unroll
            for (int it = 0; it < 2; ++it) {
                const int i = tid + 256 * it;    // 512 float4 slots
                const int row = i >> 3;
                const int kc = (i & 7) * 4;
                const int grow = m0 + row;
                float4 v = make_float4(0.f, 0.f, 0.f, 0.f);
                if (grow < M) v = *(const float4*)&A[(size_t)grow * K + kt + kc];
                v2h p0; p0[0] = (_Float16)v.x; p0[1] = (_Float16)v.y;
                v2h p1; p1[0] = (_Float16)v.z; p1[1] = (_Float16)v.w;
                As2[(kc >> 1) + 0][row] = p0;
                As2[(kc >> 1) + 1][row] = p1;
            }
        } else {
            const __half* A = (const __half*)Av;
            #pragma unroll
            for (int it = 0; it < 2; ++it) {
                const int i = tid + 256 * it;
                const int row = i >> 3;
                const int kc = (i & 7) * 4;
                const int grow = m0 + row;
                uint2 u = make_uint2(0u, 0u);
                if (grow < M) u = *(const uint2*)&A[(size_t)grow * K + kt + kc];
                As2[(kc >> 1) + 0][row] = *(v2h*)&u.x;
                As2[(kc >> 1) + 1][row] = *(v2h*)&u.y;
            }
        }
        // ---- stage B tile (32 k x BN): straight 16B copies (preconverted) --
        {
            constexpr int BCH = (BK / 2) * (BN / 4);  // 16B chunks
            for (int i = tid; i < BCH; i += 256) {
                const int k2 = i / (BN / 4);
                const int n4 = (i % (BN / 4)) * 4;
                *(float4*)&Bs2[k2][n4] =
                    *(const float4*)&Bh[(size_t)(kt / 2 + k2) * BN + n4];
            }
        }
        __syncthreads();
        #pragma unroll
        for (int k2 = 0; k2 < BK / 2; ++k2) {
            // A: one 16B read (ty*16B aligned; broadcast across tx groups)
            const float4 af = *(const float4*)&As2[k2][ty * 4];
            const v2h* a_ = (const v2h*)&af;
            v2h b_[MN];
            if (BN == 128) {
                // tx*8 v2h = tx*32B: 16B-aligned -> two wide reads
                const float4 bf0 = *(const float4*)&Bs2[k2][tx * MN];
                const float4 bf1 = *(const float4*)&Bs2[k2][tx * MN + 4];
                *(float4*)&b_[0] = bf0;
                *(float4*)&b_[4] = bf1;
            } else {
                #pragma unroll
                for (int j = 0; j < MN; ++j) b_[j] = Bs2[k2][tx * MN + j];
            }
            #pragma unroll
            for (int i = 0; i < 4; ++i)
                #pragma unroll
                for (int j = 0; j < MN; ++j)
                    acc[i][j] = __builtin_amdgcn_fdot2(a_[i], b_[j], acc[i][j], false);
        }
        __syncthreads();
    }
    // ---- epilogue: fp16 C write + alpha partial reduction ----
    const int cbase = tx * MN;
    const int head = cbase / C;      // MN cols always within one head
    #pragma unroll
    for (int i = 0; i < 4; ++i) {
        const int grow = m0 + ty * 4 + i;
        if (grow < M) {
            #pragma unroll
            for (int j = 0; j < MN; j += 2) {
                const __half2 h = __floats2half2_rn(acc[i][j], acc[i][j + 1]);
                *(__half2*)&Cout[(size_t)grow * BN + cbase + j] = h;
            }
            float part = 0.f;
            #pragma unroll
            for (int j = 0; j < MN; ++j) part += acc[i][j] * aq[cbase + j];
            atomicAdd(&sred[ty * 4 + i][head], part);
        }
    }
    __syncthreads();
    {
        const int row = m0 + (tid >> 2);
        if (row < M)
            sa[row * 4 + (tid & 3)] =
                1.0f / (1.0f + __expf(-sred[tid >> 2][tid & 3]));
    }
}

// ---- prep: weight fp16 k-paired conversion (blocks < CVB) || dst histogram --
__global__ __launch_bounds__(256)
void prep_k(const float* __restrict__ lin1, const float* __restrict__ lin2,
            __half2* __restrict__ l1h, __half2* __restrict__ l2h,
            const int* __restrict__ dst, int* __restrict__ deg,
            int CVB, int E) {
    if ((int)blockIdx.x < CVB) {
        const int t = blockIdx.x * 256 + threadIdx.x;
        if (t < 128 * 128) {
            const int k2 = t >> 7, nn = t & 127;
            l1h[t] = __floats2half2_rn(lin1[(2 * k2) * 128 + nn],
                                       lin1[(2 * k2 + 1) * 128 + nn]);
        } else {
            const int u = t - 128 * 128;
            if (u < 64 * 160) {
                const int k2 = u / 160, nn = u % 160;
                l2h[u] = __floats2half2_rn(lin2[(2 * k2) * 160 + nn],
                                           lin2[(2 * k2 + 1) * 160 + nn]);
            }
        }
    } else {
        const int e = ((int)blockIdx.x - CVB) * 256 + threadIdx.x;
        if (e < E) atomicAdd(&deg[dst[e]], 1);
    }
}

// ---------------- CSR scan ----------------
__global__ __launch_bounds__(256)
void scan1_k(const int* __restrict__ deg, int* __restrict__ ro,
             int* __restrict__ bsum, int n) {
    __shared__ int s[256];
    int i = blockIdx.x * 256 + threadIdx.x;
    int v = (i < n) ? deg[i] : 0;
    s[threadIdx.x] = v;
    __syncthreads();
    for (int off = 1; off < 256; off <<= 1) {
        int t = (threadIdx.x >= off) ? s[threadIdx.x - off] : 0;
        __syncthreads();
        s[threadIdx.x] += t;
        __syncthreads();
    }
    if (i < n) ro[i] = s[threadIdx.x] - v;
    if (threadIdx.x == 255) bsum[blockIdx.x] = s[255];
}

__global__ __launch_bounds__(256)
void scan23_k(int* __restrict__ ro, int* __restrict__ cur,
              const int* __restrict__ bsum, int n, int E, int nb) {
    __shared__ int s[256];
    int v = ((int)threadIdx.x < nb) ? bsum[threadIdx.x] : 0;
    s[threadIdx.x] = v;
    __syncthreads();
    for (int off = 1; off < 256; off <<= 1) {
        int t = (threadIdx.x >= off) ? s[threadIdx.x - off] : 0;
        __syncthreads();
        s[threadIdx.x] += t;
        __syncthreads();
    }
    const int pref = (blockIdx.x == 0) ? 0 : s[blockIdx.x - 1];  // exclusive
    const int i = blockIdx.x * 256 + threadIdx.x;
    if (i < n) {
        const int r = ro[i] + pref;
        ro[i] = r;
        cur[i] = r;
    }
    if (i == 0) ro[n] = E;
}

// ---- front2: layer-1 GEMM+alpha (blocks < MB) || CSR scatter (rest) ----
__global__ __launch_bounds__(256)
void front2_k(const float* __restrict__ x, const __half2* __restrict__ l1h,
              const float* __restrict__ attq1, __half* __restrict__ xh,
              float* __restrict__ sa, const int* __restrict__ src,
              const int* __restrict__ dst, int* __restrict__ cur,
              int* __restrict__ csr_src, int M, int K, int MB, int E) {
    if ((int)blockIdx.x < MB) {
        gemm_alpha_body<128, false>(x, l1h, attq1, xh, sa, M, K, blockIdx.x);
    } else {
        const int e = ((int)blockIdx.x - MB) * 256 + threadIdx.x;
        if (e < E) {
            const int d = dst[e];
            const int pos = atomicAdd(&cur[d], 1);
            csr_src[pos] = src[e];
        }
    }
}

__global__ __launch_bounds__(256)
void gemm2_k(const __half* __restrict__ acc16, const __half2* __restrict__ l2h,
             const float* __restrict__ attq2, __half* __restrict__ xh,
             float* __restrict__ sa, int M, int K) {
    gemm_alpha_body<160, true>(acc16, l2h, attq2, xh, sa, M, K, blockIdx.x);
}

// ---------------- fused logit+softmax+aggregate+epilogue (fp16 xh) ----------
// R15 config: ONE WAVE PER BLOCK (64 threads), one node per block — measured
// optimum (R16/R17 multi-wave variants both regressed).
template <int C, bool CONCAT>
__global__ __launch_bounds__(64)
void fused_edge_k(const int* __restrict__ ro, const int* __restrict__ csr_src,
                  const __half* __restrict__ xh, const float* __restrict__ sa,
                  const float* __restrict__ attv, const float* __restrict__ bias,
                  void* __restrict__ outp, int n) {
    constexpr int HC = 4 * C;
    constexpr int QH = C / 4;        // 4-half chunks per head quarter
    constexpr int CHUNK = 64;        // edges per super-chunk
    constexpr bool DUAL = (C <= 32);
    const int lane = threadIdx.x;
    const int node = blockIdx.x;

    __shared__ float wbuf[CHUNK * 4];
    __shared__ int sibuf[CHUNK];
    __shared__ __half2 avs[HC / 2];
    for (int i = lane; i < HC / 2; i += 64)
        avs[i] = __floats2half2_rn(attv[2 * i], attv[2 * i + 1]);
    __syncthreads();
    if (node >= n) return;

    const int s0 = ro[node], s1 = ro[node + 1];

    // logit mapping
    const int e_loc = lane >> 2;
    const int h_l = lane & 3;
    const float sad = sa[node * 4 + h_l];
    const __half2 c505 = __floats2half2_rn(0.505f, 0.505f);
    const __half2 c495 = __floats2half2_rn(0.495f, 0.495f);

    // hoisted dst-row quarter as half2
    __half2 xd[QH * 2];
    {
        const __half* p = &xh[(size_t)node * HC + h_l * C];
        #pragma unroll
        for (int i = 0; i < QH; ++i) {
            const uint2 u = *(const uint2*)&p[i * 4];
            xd[2 * i] = *(const __half2*)&u.x;
            xd[2 * i + 1] = *(const __half2*)&u.y;
        }
    }

    // aggregation mapping
    const int half_ = DUAL ? (lane >> 5) : 0;
    const int q = DUAL ? (lane & 31) : lane;
    const int h_a = (q < C) ? (q / QH) : 0;

    float4 acc = make_float4(0.f, 0.f, 0.f, 0.f);
    float ssum = 0.f;

    for (int base = s0; base < s1; base += CHUNK) {
        const int cnt = min(CHUNK, s1 - base);
        const int npass = (cnt + 15) >> 4;
        // ---- logit passes: 16 edges x 4 heads per pass, packed fp16 ----
        for (int p = 0; p < npass; ++p) {
            const int eidx = p * 16 + e_loc;
            const int j = base + eidx;
            float w = 0.f;
            int si = 0;
            if (j < s1) {
                si = csr_src[j];
                const float sas = sa[si * 4 + h_l];
                const float wa = 1.0f - fabsf(sad - sas);
                const __half* xs = &xh[(size_t)si * HC + h_l * C];
                float wb = 0.f;
                #pragma unroll
                for (int i = 0; i < QH; ++i) {
                    const uint2 u = *(const uint2*)&xs[i * 4];
                    const __half2 a0 = *(const __half2*)&u.x;
                    const __half2 a1 = *(const __half2*)&u.y;
                    const __half2 t0 = __hadd2(a0, xd[2 * i]);
                    const __half2 t1 = __hadd2(a1, xd[2 * i + 1]);
                    const __half2 l0 = __hfma2(t0, c505, __hmul2(habs2_(t0), c495));
                    const __half2 l1 = __hfma2(t1, c505, __hmul2(habs2_(t1), c495));
                    wb = fdot2_(l0, avs[h_l * QH * 2 + 2 * i], wb);
                    wb = fdot2_(l1, avs[h_l * QH * 2 + 2 * i + 1], wb);
                }
                w = __expf(fminf(wa * wb, 60.f));  // inf-guard only
                ssum += w;
            }
            wbuf[eidx * 4 + h_l] = w;
            if (h_l == 0) sibuf[eidx] = si;
        }
        // ---- aggregation: padded slots carry w=0/si=0, no guards ----
        const int padded = npass << 4;
        if (q < C) {
            if (DUAL) {
                for (int i = 0; i < padded; i += 8) {
                    const int e0 = i + half_, e1 = i + half_ + 2;
                    const int e2 = i + half_ + 4, e3 = i + half_ + 6;
                    const int i0 = sibuf[e0], i1 = sibuf[e1];
                    const int i2 = sibuf[e2], i3 = sibuf[e3];
                    const float w0 = wbuf[e0 * 4 + h_a];
                    const float w1 = wbuf[e1 * 4 + h_a];
                    const float w2 = wbuf[e2 * 4 + h_a];
                    const float w3 = wbuf[e3 * 4 + h_a];
                    const float4 v0 = ldh4(&xh[(size_t)i0 * HC + q * 4]);
                    const float4 v1 = ldh4(&xh[(size_t)i1 * HC + q * 4]);
                    const float4 v2 = ldh4(&xh[(size_t)i2 * HC + q * 4]);
                    const float4 v3 = ldh4(&xh[(size_t)i3 * HC + q * 4]);
                    acc.x += w0 * v0.x + w1 * v1.x + w2 * v2.x + w3 * v3.x;
                    acc.y += w0 * v0.y + w1 * v1.y + w2 * v2.y + w3 * v3.y;
                    acc.z += w0 * v0.z + w1 * v1.z + w2 * v2.z + w3 * v3.z;
                    acc.w += w0 * v0.w + w1 * v1.w + w2 * v2.w + w3 * v3.w;
                }
            } else {
                for (int i = 0; i < padded; i += 4) {
                    const int i0 = sibuf[i],     i1 = sibuf[i + 1];
                    const int i2 = sibuf[i + 2], i3 = sibuf[i + 3];
                    const float w0 = wbuf[(i + 0) * 4 + h_a];
                    const float w1 = wbuf[(i + 1) * 4 + h_a];
                    const float w2 = wbuf[(i + 2) * 4 + h_a];
                    const float w3 = wbuf[(i + 3) * 4 + h_a];
                    const float4 v0 = ldh4(&xh[(size_t)i0 * HC + q * 4]);
                    const float4 v1 = ldh4(&xh[(size_t)i1 * HC + q * 4]);
                    const float4 v2 = ldh4(&xh[(size_t)i2 * HC + q * 4]);
                    const float4 v3 = ldh4(&xh[(size_t)i3 * HC + q * 4]);
                    acc.x += w0 * v0.x + w1 * v1.x + w2 * v2.x + w3 * v3.x;
                    acc.y += w0 * v0.y + w1 * v1.y + w2 * v2.y + w3 * v3.y;
                    acc.z += w0 * v0.z + w1 * v1.z + w2 * v2.z + w3 * v3.z;
                    acc.w += w0 * v0.w + w1 * v1.w + w2 * v2.w + w3 * v3.w;
                }
            }
        }
    }

    // combine dual halves
    if (DUAL) {
        acc.x += __shfl_xor(acc.x, 32, 64);
        acc.y += __shfl_xor(acc.y, 32, 64);
        acc.z += __shfl_xor(acc.z, 32, 64);
        acc.w += __shfl_xor(acc.w, 32, 64);
    }

    // per-head sum of weights: reduce across lanes sharing (lane & 3)
    #pragma unroll
    for (int off = 4; off < 64; off <<= 1) ssum += __shfl_xor(ssum, off, 64);
    const float stot = __shfl(ssum, h_a, 64);
    const float inv = 1.0f / (stot + 1e-20f);
    acc.x *= inv; acc.y *= inv; acc.z *= inv; acc.w *= inv;

    if (CONCAT) {
        if (q < C && half_ == 0) {
            const float4 b = ((const float4*)bias)[q];
            float4 v = make_float4(acc.x + b.x, acc.y + b.y, acc.z + b.z, acc.w + b.w);
            v.x = v.x > 0.f ? v.x : __expf(v.x) - 1.0f;
            v.y = v.y > 0.f ? v.y : __expf(v.y) - 1.0f;
            v.z = v.z > 0.f ? v.z : __expf(v.z) - 1.0f;
            v.w = v.w > 0.f ? v.w : __expf(v.w) - 1.0f;
            __half* o16 = (__half*)outp;
            const __half2 h01 = __floats2half2_rn(v.x, v.y);
            const __half2 h23 = __floats2half2_rn(v.z, v.w);
            uint2 u;
            u.x = *(const unsigned*)&h01;
            u.y = *(const unsigned*)&h23;
            *(uint2*)&o16[(size_t)node * HC + q * 4] = u;
        }
    } else {
        // head-mean via shuffles
        const int qq = (q < QH) ? q : 0;
        const float x1 = __shfl(acc.x, qq + QH, 64);
        const float y1 = __shfl(acc.y, qq + QH, 64);
        const float z1 = __shfl(acc.z, qq + QH, 64);
        const float w1 = __shfl(acc.w, qq + QH, 64);
        const float x2 = __shfl(acc.x, qq + 2 * QH, 64);
        const float y2 = __shfl(acc.y, qq + 2 * QH, 64);
        const float z2 = __shfl(acc.z, qq + 2 * QH, 64);
        const float w2 = __shfl(acc.w, qq + 2 * QH, 64);
        const float x3 = __shfl(acc.x, qq + 3 * QH, 64);
        const float y3 = __shfl(acc.y, qq + 3 * QH, 64);
        const float z3 = __shfl(acc.z, qq + 3 * QH, 64);
        const float w3 = __shfl(acc.w, qq + 3 * QH, 64);
        if (q < QH && half_ == 0) {
            float* of = (float*)outp;
            const float4 b = ((const float4*)bias)[q];
            float4 v;
            v.x = 0.25f * (acc.x + x1 + x2 + x3) + b.x;
            v.y = 0.25f * (acc.y + y1 + y2 + y3) + b.y;
            v.z = 0.25f * (acc.z + z1 + z2 + z3) + b.z;
            v.w = 0.25f * (acc.w + w1 + w2 + w3) + b.w;
            *(float4*)&of[(size_t)node * C + q * 4] = v;
        }
    }
}

extern "C" void kernel_launch(void* const* d_in, const int* in_sizes, int n_in,
                              void* d_out, int out_size, void* d_ws, size_t ws_size,
                              hipStream_t stream) {
    const float* x      = (const float*)d_in[0];
    const int*   src    = (const int*)d_in[1];
    const int*   dst    = (const int*)d_in[2];
    const float* lin1   = (const float*)d_in[3];
    const float* att_q1 = (const float*)d_in[4];
    const float* att_v1 = (const float*)d_in[5];
    const float* bias1  = (const float*)d_in[6];
    const float* lin2   = (const float*)d_in[7];
    const float* att_q2 = (const float*)d_in[8];
    const float* att_v2 = (const float*)d_in[9];
    const float* bias2  = (const float*)d_in[10];
    float* outp = (float*)d_out;

    const int n = in_sizes[0] / 256;
    const int E = in_sizes[1];
    const int nh = n * HEADS;
    const int NB = (n + 255) / 256;

    char* wsb = (char*)d_ws;
    size_t o = 0;
    __half* xh     = (__half*)(wsb + o); o += (size_t)n * 160 * 2;
    __half* acc16  = (__half*)(wsb + o); o += (size_t)n * 128 * 2;
    float* sa      = (float*)(wsb + o); o += (size_t)nh * 4;
    int* csr_src   = (int*)(wsb + o); o += (size_t)E * 4;
    int* deg       = (int*)(wsb + o); o += (size_t)n * 4;
    int* ro        = (int*)(wsb + o); o += (size_t)(n + 1) * 4;
    int* cur       = (int*)(wsb + o); o += (size_t)n * 4;
    int* bsum      = (int*)(wsb + o); o += 256 * 4;
    __half2* l1h   = (__half2*)(wsb + o); o += (size_t)128 * 128 * 4;
    __half2* l2h   = (__half2*)(wsb + o); o += (size_t)64 * 160 * 4;

    dim3 blk(256);
    const int EG = (E + 255) / 256;
    const int MB = (n + 63) / 64;
    const int CVB = (128 * 128 + 64 * 160 + 255) / 256;

    // ---- prep: weight conversion || dst histogram ----
    hipMemsetAsync(deg, 0, (size_t)n * 4, stream);
    prep_k<<<CVB + EG, blk, 0, stream>>>(lin1, lin2, l1h, l2h, dst, deg, CVB, E);
    // ---- CSR scan (2 kernels) ----
    scan1_k<<<NB, blk, 0, stream>>>(deg, ro, bsum, n);
    scan23_k<<<NB, blk, 0, stream>>>(ro, cur, bsum, n, E, NB);
    // ---- front2: layer-1 GEMM+alpha || CSR scatter ----
    front2_k<<<MB + EG, blk, 0, stream>>>(x, l1h, att_q1, xh, sa, src, dst,
                                          cur, csr_src, n, 256, MB, E);
    // ---- layer 1 edge phase (1 wave / node) ----
    fused_edge_k<32, true><<<n, dim3(64), 0, stream>>>(ro, csr_src, xh, sa, att_v1, bias1, acc16, n);
    // ---- layer 2 ----
    gemm2_k<<<MB, blk, 0, stream>>>(acc16, l2h, att_q2, xh, sa, n, 128);
    fused_edge_k<40, false><<<n, dim3(64), 0, stream>>>(ro, csr_src, xh, sa, att_v2, bias2, outp, n);
}

// Round 19
// 293.841 us; speedup vs baseline: 1.1139x; 1.0309x over previous
//
#include <hip/hip_runtime.h>
#include <hip/hip_fp16.h>

#define HEADS 4

typedef _Float16 v2h __attribute__((ext_vector_type(2)));

// load 4 consecutive halfs (8B aligned) -> float4
__device__ __forceinline__ float4 ldh4(const __half* p) {
    const uint2 u = *(const uint2*)p;
    const float2 a = __half22float2(*(const __half2*)&u.x);
    const float2 b = __half22float2(*(const __half2*)&u.y);
    return make_float4(a.x, a.y, b.x, b.y);
}

__device__ __forceinline__ __half2 habs2_(__half2 x) {
    unsigned u = *reinterpret_cast<unsigned*>(&x) & 0x7FFF7FFFu;
    return *reinterpret_cast<__half2*>(&u);
}

__device__ __forceinline__ float fdot2_(__half2 a, __half2 b, float c) {
    return __builtin_amdgcn_fdot2(*(v2h*)&a, *(v2h*)&b, c, false);
}

// ------- wide GEMM + fused alpha: C[M,BN] = A[M,K] @ B[K,BN] -------
// BM=64, BK=32, 256 threads, micro-tile 4 x (BN/16).  (R15 version)
template <int BN, bool AHALF>
__device__ __forceinline__ void gemm_alpha_body(
    const void* __restrict__ Av, const __half2* __restrict__ Bh,
    const float* __restrict__ attq, __half* __restrict__ Cout,
    float* __restrict__ sa, int M, int K, int bid) {
    constexpr int BM = 64, BK = 32;
    constexpr int MN = BN / 16;
    constexpr int C = BN / 4;
    __shared__ v2h As2[BK / 2][BM];
    __shared__ v2h Bs2[BK / 2][BN];
    __shared__ float sred[BM][4];
    __shared__ float aq[BN];
    const int m0 = bid * BM;
    const int tid = threadIdx.x;
    const int ty = tid >> 4;   // 0..15
    const int tx = tid & 15;   // 0..15
    for (int i = tid; i < BN; i += 256) aq[i] = attq[i];
    sred[tid >> 2][tid & 3] = 0.f;   // 256 == BM*4
    float acc[4][MN] = {};

    for (int kt = 0; kt < K; kt += BK) {
        // ---- stage A tile (64 rows x 32 k), k-paired half2, transposed ----
        if (!AHALF) {
            const float* A = (const float*)Av;
            #pragma unroll
            for (int it = 0; it < 2; ++it) {
                const int i = tid + 256 * it;    // 512 float4 slots
                const int row = i >> 3;
                const int kc = (i & 7) * 4;
                const int grow = m0 + row;
                float4 v = make_float4(0.f, 0.f, 0.f, 0.f);
                if (grow < M) v = *(const float4*)&A[(size_t)grow * K + kt + kc];
                v2h p0; p0[0] = (_Float16)v.x; p0[1] = (_Float16)v.y;
                v2h p1; p1[0] = (_Float16)v.z; p1[1] = (_Float16)v.w;
                As2[(kc >> 1) + 0][row] = p0;
                As2[(kc >> 1) + 1][row] = p1;
            }
        } else {
            const __half* A = (const __half*)Av;
            #pragma unroll
            for (int it = 0; it < 2; ++it) {
                const int i = tid + 256 * it;
                const int row = i >> 3;
                const int kc = (i & 7) * 4;
                const int grow = m0 + row;
                uint2 u = make_uint2(0u, 0u);
                if (grow < M) u = *(const uint2*)&A[(size_t)grow * K + kt + kc];
                As2[(kc >> 1) + 0][row] = *(v2h*)&u.x;
                As2[(kc >> 1) + 1][row] = *(v2h*)&u.y;
            }
        }
        // ---- stage B tile (32 k x BN): straight 16B copies (preconverted) --
        {
            constexpr int BCH = (BK / 2) * (BN / 4);  // 16B chunks
            for (int i = tid; i < BCH; i += 256) {
                const int k2 = i / (BN / 4);
                const int n4 = (i % (BN / 4)) * 4;
                *(float4*)&Bs2[k2][n4] =
                    *(const float4*)&Bh[(size_t)(kt / 2 + k2) * BN + n4];
            }
        }
        __syncthreads();
        #pragma unroll
        for (int k2 = 0; k2 < BK / 2; ++k2) {
            v2h a_[4], b_[MN];
            #pragma unroll
            for (int i = 0; i < 4; ++i) a_[i] = As2[k2][ty * 4 + i];
            #pragma unroll
            for (int j = 0; j < MN; ++j) b_[j] = Bs2[k2][tx * MN + j];
            #pragma unroll
            for (int i = 0; i < 4; ++i)
                #pragma unroll
                for (int j = 0; j < MN; ++j)
                    acc[i][j] = __builtin_amdgcn_fdot2(a_[i], b_[j], acc[i][j], false);
        }
        __syncthreads();
    }
    // ---- epilogue: fp16 C write + alpha partial reduction ----
    const int cbase = tx * MN;
    const int head = cbase / C;      // MN cols always within one head
    #pragma unroll
    for (int i = 0; i < 4; ++i) {
        const int grow = m0 + ty * 4 + i;
        if (grow < M) {
            #pragma unroll
            for (int j = 0; j < MN; j += 2) {
                const __half2 h = __floats2half2_rn(acc[i][j], acc[i][j + 1]);
                *(__half2*)&Cout[(size_t)grow * BN + cbase + j] = h;
            }
            float part = 0.f;
            #pragma unroll
            for (int j = 0; j < MN; ++j) part += acc[i][j] * aq[cbase + j];
            atomicAdd(&sred[ty * 4 + i][head], part);
        }
    }
    __syncthreads();
    {
        const int row = m0 + (tid >> 2);
        if (row < M)
            sa[row * 4 + (tid & 3)] =
                1.0f / (1.0f + __expf(-sred[tid >> 2][tid & 3]));
    }
}

// ---- prep: weight fp16 k-paired conversion (blocks < CVB) || dst histogram --
__global__ __launch_bounds__(256)
void prep_k(const float* __restrict__ lin1, const float* __restrict__ lin2,
            __half2* __restrict__ l1h, __half2* __restrict__ l2h,
            const int* __restrict__ dst, int* __restrict__ deg,
            int CVB, int E) {
    if ((int)blockIdx.x < CVB) {
        const int t = blockIdx.x * 256 + threadIdx.x;
        if (t < 128 * 128) {
            const int k2 = t >> 7, nn = t & 127;
            l1h[t] = __floats2half2_rn(lin1[(2 * k2) * 128 + nn],
                                       lin1[(2 * k2 + 1) * 128 + nn]);
        } else {
            const int u = t - 128 * 128;
            if (u < 64 * 160) {
                const int k2 = u / 160, nn = u % 160;
                l2h[u] = __floats2half2_rn(lin2[(2 * k2) * 160 + nn],
                                           lin2[(2 * k2 + 1) * 160 + nn]);
            }
        }
    } else {
        const int e = ((int)blockIdx.x - CVB) * 256 + threadIdx.x;
        if (e < E) atomicAdd(&deg[dst[e]], 1);
    }
}

// ---------------- CSR scan ----------------
__global__ __launch_bounds__(256)
void scan1_k(const int* __restrict__ deg, int* __restrict__ ro,
             int* __restrict__ bsum, int n) {
    __shared__ int s[256];
    int i = blockIdx.x * 256 + threadIdx.x;
    int v = (i < n) ? deg[i] : 0;
    s[threadIdx.x] = v;
    __syncthreads();
    for (int off = 1; off < 256; off <<= 1) {
        int t = (threadIdx.x >= off) ? s[threadIdx.x - off] : 0;
        __syncthreads();
        s[threadIdx.x] += t;
        __syncthreads();
    }
    if (i < n) ro[i] = s[threadIdx.x] - v;
    if (threadIdx.x == 255) bsum[blockIdx.x] = s[255];
}

__global__ __launch_bounds__(256)
void scan23_k(int* __restrict__ ro, int* __restrict__ cur,
              const int* __restrict__ bsum, int n, int E, int nb) {
    __shared__ int s[256];
    int v = ((int)threadIdx.x < nb) ? bsum[threadIdx.x] : 0;
    s[threadIdx.x] = v;
    __syncthreads();
    for (int off = 1; off < 256; off <<= 1) {
        int t = (threadIdx.x >= off) ? s[threadIdx.x - off] : 0;
        __syncthreads();
        s[threadIdx.x] += t;
        __syncthreads();
    }
    const int pref = (blockIdx.x == 0) ? 0 : s[blockIdx.x - 1];  // exclusive
    const int i = blockIdx.x * 256 + threadIdx.x;
    if (i < n) {
        const int r = ro[i] + pref;
        ro[i] = r;
        cur[i] = r;
    }
    if (i == 0) ro[n] = E;
}

// ---- front2: layer-1 GEMM+alpha (blocks < MB) || CSR scatter (rest) ----
__global__ __launch_bounds__(256)
void front2_k(const float* __restrict__ x, const __half2* __restrict__ l1h,
              const float* __restrict__ attq1, __half* __restrict__ xh,
              float* __restrict__ sa, const int* __restrict__ src,
              const int* __restrict__ dst, int* __restrict__ cur,
              int* __restrict__ csr_src, int M, int K, int MB, int E) {
    if ((int)blockIdx.x < MB) {
        gemm_alpha_body<128, false>(x, l1h, attq1, xh, sa, M, K, blockIdx.x);
    } else {
        const int e = ((int)blockIdx.x - MB) * 256 + threadIdx.x;
        if (e < E) {
            const int d = dst[e];
            const int pos = atomicAdd(&cur[d], 1);
            csr_src[pos] = src[e];
        }
    }
}

__global__ __launch_bounds__(256)
void gemm2_k(const __half* __restrict__ acc16, const __half2* __restrict__ l2h,
             const float* __restrict__ attq2, __half* __restrict__ xh,
             float* __restrict__ sa, int M, int K) {
    gemm_alpha_body<160, true>(acc16, l2h, attq2, xh, sa, M, K, blockIdx.x);
}

// ---------------- fused logit+softmax+aggregate+epilogue (fp16 xh) ----------
// ONE WAVE PER BLOCK (64 threads), one node per block: measured optimum.
template <int C, bool CONCAT>
__global__ __launch_bounds__(64)
void fused_edge_k(const int* __restrict__ ro, const int* __restrict__ csr_src,
                  const __half* __restrict__ xh, const float* __restrict__ sa,
                  const float* __restrict__ attv, const float* __restrict__ bias,
                  void* __restrict__ outp, int n) {
    constexpr int HC = 4 * C;
    constexpr int QH = C / 4;        // 4-half chunks per head quarter
    constexpr int CHUNK = 64;        // edges per super-chunk
    constexpr bool DUAL = (C <= 32);
    const int lane = threadIdx.x;
    const int node = blockIdx.x;

    __shared__ float wbuf[CHUNK * 4];
    __shared__ int sibuf[CHUNK];
    __shared__ __half2 avs[HC / 2];
    for (int i = lane; i < HC / 2; i += 64)
        avs[i] = __floats2half2_rn(attv[2 * i], attv[2 * i + 1]);
    __syncthreads();
    if (node >= n) return;

    const int s0 = ro[node], s1 = ro[node + 1];

    // logit mapping
    const int e_loc = lane >> 2;
    const int h_l = lane & 3;
    const float sad = sa[node * 4 + h_l];
    const __half2 c505 = __floats2half2_rn(0.505f, 0.505f);
    const __half2 c495 = __floats2half2_rn(0.495f, 0.495f);

    // hoisted dst-row quarter as half2
    __half2 xd[QH * 2];
    {
        const __half* p = &xh[(size_t)node * HC + h_l * C];
        #pragma unroll
        for (int i = 0; i < QH; ++i) {
            const uint2 u = *(const uint2*)&p[i * 4];
            xd[2 * i] = *(const __half2*)&u.x;
            xd[2 * i + 1] = *(const __half2*)&u.y;
        }
    }

    // aggregation mapping
    const int half_ = DUAL ? (lane >> 5) : 0;
    const int q = DUAL ? (lane & 31) : lane;
    const int h_a = (q < C) ? (q / QH) : 0;

    float4 acc = make_float4(0.f, 0.f, 0.f, 0.f);
    float ssum = 0.f;

    for (int base = s0; base < s1; base += CHUNK) {
        const int cnt = min(CHUNK, s1 - base);
        const int npass = (cnt + 15) >> 4;
        // ---- logit passes: 16 edges x 4 heads per pass, packed fp16 ----
        for (int p = 0; p < npass; ++p) {
            const int eidx = p * 16 + e_loc;
            const int j = base + eidx;
            float w = 0.f;
            int si = 0;
            if (j < s1) {
                si = csr_src[j];
                const float sas = sa[si * 4 + h_l];
                const float wa = 1.0f - fabsf(sad - sas);
                const __half* xs = &xh[(size_t)si * HC + h_l * C];
                float wb = 0.f;
                #pragma unroll
                for (int i = 0; i < QH; ++i) {
                    const uint2 u = *(const uint2*)&xs[i * 4];
                    const __half2 a0 = *(const __half2*)&u.x;
                    const __half2 a1 = *(const __half2*)&u.y;
                    const __half2 t0 = __hadd2(a0, xd[2 * i]);
                    const __half2 t1 = __hadd2(a1, xd[2 * i + 1]);
                    const __half2 l0 = __hfma2(t0, c505, __hmul2(habs2_(t0), c495));
                    const __half2 l1 = __hfma2(t1, c505, __hmul2(habs2_(t1), c495));
                    wb = fdot2_(l0, avs[h_l * QH * 2 + 2 * i], wb);
                    wb = fdot2_(l1, avs[h_l * QH * 2 + 2 * i + 1], wb);
                }
                w = __expf(fminf(wa * wb, 60.f));  // inf-guard only
                ssum += w;
            }
            wbuf[eidx * 4 + h_l] = w;
            if (h_l == 0) sibuf[eidx] = si;
        }
        // ---- aggregation: padded slots carry w=0/si=0, no guards ----
        const int padded = npass << 4;
        if (q < C) {
            if (DUAL) {
                for (int i = 0; i < padded; i += 8) {
                    const int e0 = i + half_, e1 = i + half_ + 2;
                    const int e2 = i + half_ + 4, e3 = i + half_ + 6;
                    const int i0 = sibuf[e0], i1 = sibuf[e1];
                    const int i2 = sibuf[e2], i3 = sibuf[e3];
                    const float w0 = wbuf[e0 * 4 + h_a];
                    const float w1 = wbuf[e1 * 4 + h_a];
                    const float w2 = wbuf[e2 * 4 + h_a];
                    const float w3 = wbuf[e3 * 4 + h_a];
                    const float4 v0 = ldh4(&xh[(size_t)i0 * HC + q * 4]);
                    const float4 v1 = ldh4(&xh[(size_t)i1 * HC + q * 4]);
                    const float4 v2 = ldh4(&xh[(size_t)i2 * HC + q * 4]);
                    const float4 v3 = ldh4(&xh[(size_t)i3 * HC + q * 4]);
                    acc.x += w0 * v0.x + w1 * v1.x + w2 * v2.x + w3 * v3.x;
                    acc.y += w0 * v0.y + w1 * v1.y + w2 * v2.y + w3 * v3.y;
                    acc.z += w0 * v0.z + w1 * v1.z + w2 * v2.z + w3 * v3.z;
                    acc.w += w0 * v0.w + w1 * v1.w + w2 * v2.w + w3 * v3.w;
                }
            } else {
                for (int i = 0; i < padded; i += 4) {
                    const int i0 = sibuf[i],     i1 = sibuf[i + 1];
                    const int i2 = sibuf[i + 2], i3 = sibuf[i + 3];
                    const float w0 = wbuf[(i + 0) * 4 + h_a];
                    const float w1 = wbuf[(i + 1) * 4 + h_a];
                    const float w2 = wbuf[(i + 2) * 4 + h_a];
                    const float w3 = wbuf[(i + 3) * 4 + h_a];
                    const float4 v0 = ldh4(&xh[(size_t)i0 * HC + q * 4]);
                    const float4 v1 = ldh4(&xh[(size_t)i1 * HC + q * 4]);
                    const float4 v2 = ldh4(&xh[(size_t)i2 * HC + q * 4]);
                    const float4 v3 = ldh4(&xh[(size_t)i3 * HC + q * 4]);
                    acc.x += w0 * v0.x + w1 * v1.x + w2 * v2.x + w3 * v3.x;
                    acc.y += w0 * v0.y + w1 * v1.y + w2 * v2.y + w3 * v3.y;
                    acc.z += w0 * v0.z + w1 * v1.z + w2 * v2.z + w3 * v3.z;
                    acc.w += w0 * v0.w + w1 * v1.w + w2 * v2.w + w3 * v3.w;
                }
            }
        }
    }

    // combine dual halves
    if (DUAL) {
        acc.x += __shfl_xor(acc.x, 32, 64);
        acc.y += __shfl_xor(acc.y, 32, 64);
        acc.z += __shfl_xor(acc.z, 32, 64);
        acc.w += __shfl_xor(acc.w, 32, 64);
    }

    // per-head sum of weights: reduce across lanes sharing (lane & 3)
    #pragma unroll
    for (int off = 4; off < 64; off <<= 1) ssum += __shfl_xor(ssum, off, 64);
    const float stot = __shfl(ssum, h_a, 64);
    const float inv = 1.0f / (stot + 1e-20f);
    acc.x *= inv; acc.y *= inv; acc.z *= inv; acc.w *= inv;

    if (CONCAT) {
        if (q < C && half_ == 0) {
            const float4 b = ((const float4*)bias)[q];
            float4 v = make_float4(acc.x + b.x, acc.y + b.y, acc.z + b.z, acc.w + b.w);
            v.x = v.x > 0.f ? v.x : __expf(v.x) - 1.0f;
            v.y = v.y > 0.f ? v.y : __expf(v.y) - 1.0f;
            v.z = v.z > 0.f ? v.z : __expf(v.z) - 1.0f;
            v.w = v.w > 0.f ? v.w : __expf(v.w) - 1.0f;
            __half* o16 = (__half*)outp;
            const __half2 h01 = __floats2half2_rn(v.x, v.y);
            const __half2 h23 = __floats2half2_rn(v.z, v.w);
            uint2 u;
            u.x = *(const unsigned*)&h01;
            u.y = *(const unsigned*)&h23;
            *(uint2*)&o16[(size_t)node * HC + q * 4] = u;
        }
    } else {
        // head-mean via shuffles
        const int qq = (q < QH) ? q : 0;
        const float x1 = __shfl(acc.x, qq + QH, 64);
        const float y1 = __shfl(acc.y, qq + QH, 64);
        const float z1 = __shfl(acc.z, qq + QH, 64);
        const float w1 = __shfl(acc.w, qq + QH, 64);
        const float x2 = __shfl(acc.x, qq + 2 * QH, 64);
        const float y2 = __shfl(acc.y, qq + 2 * QH, 64);
        const float z2 = __shfl(acc.z, qq + 2 * QH, 64);
        const float w2 = __shfl(acc.w, qq + 2 * QH, 64);
        const float x3 = __shfl(acc.x, qq + 3 * QH, 64);
        const float y3 = __shfl(acc.y, qq + 3 * QH, 64);
        const float z3 = __shfl(acc.z, qq + 3 * QH, 64);
        const float w3 = __shfl(acc.w, qq + 3 * QH, 64);
        if (q < QH && half_ == 0) {
            float* of = (float*)outp;
            const float4 b = ((const float4*)bias)[q];
            float4 v;
            v.x = 0.25f * (acc.x + x1 + x2 + x3) + b.x;
            v.y = 0.25f * (acc.y + y1 + y2 + y3) + b.y;
            v.z = 0.25f * (acc.z + z1 + z2 + z3) + b.z;
            v.w = 0.25f * (acc.w + w1 + w2 + w3) + b.w;
            *(float4*)&of[(size_t)node * C + q * 4] = v;
        }
    }
}

extern "C" void kernel_launch(void* const* d_in, const int* in_sizes, int n_in,
                              void* d_out, int out_size, void* d_ws, size_t ws_size,
                              hipStream_t stream) {
    const float* x      = (const float*)d_in[0];
    const int*   src    = (const int*)d_in[1];
    const int*   dst    = (const int*)d_in[2];
    const float* lin1   = (const float*)d_in[3];
    const float* att_q1 = (const float*)d_in[4];
    const float* att_v1 = (const float*)d_in[5];
    const float* bias1  = (const float*)d_in[6];
    const float* lin2   = (const float*)d_in[7];
    const float* att_q2 = (const float*)d_in[8];
    const float* att_v2 = (const float*)d_in[9];
    const float* bias2  = (const float*)d_in[10];
    float* outp = (float*)d_out;

    const int n = in_sizes[0] / 256;
    const int E = in_sizes[1];
    const int nh = n * HEADS;
    const int NB = (n + 255) / 256;

    char* wsb = (char*)d_ws;
    size_t o = 0;
    __half* xh     = (__half*)(wsb + o); o += (size_t)n * 160 * 2;
    __half* acc16  = (__half*)(wsb + o); o += (size_t)n * 128 * 2;
    float* sa      = (float*)(wsb + o); o += (size_t)nh * 4;
    int* csr_src   = (int*)(wsb + o); o += (size_t)E * 4;
    int* deg       = (int*)(wsb + o); o += (size_t)n * 4;
    int* ro        = (int*)(wsb + o); o += (size_t)(n + 1) * 4;
    int* cur       = (int*)(wsb + o); o += (size_t)n * 4;
    int* bsum      = (int*)(wsb + o); o += 256 * 4;
    __half2* l1h   = (__half2*)(wsb + o); o += (size_t)128 * 128 * 4;
    __half2* l2h   = (__half2*)(wsb + o); o += (size_t)64 * 160 * 4;

    dim3 blk(256);
    const int EG = (E + 255) / 256;
    const int MB = (n + 63) / 64;
    const int CVB = (128 * 128 + 64 * 160 + 255) / 256;

    // ---- prep: weight conversion || dst histogram ----
    hipMemsetAsync(deg, 0, (size_t)n * 4, stream);
    prep_k<<<CVB + EG, blk, 0, stream>>>(lin1, lin2, l1h, l2h, dst, deg, CVB, E);
    // ---- CSR scan (2 kernels) ----
    scan1_k<<<NB, blk, 0, stream>>>(deg, ro, bsum, n);
    scan23_k<<<NB, blk, 0, stream>>>(ro, cur, bsum, n, E, NB);
    // ---- front2: layer-1 GEMM+alpha || CSR scatter ----
    front2_k<<<MB + EG, blk, 0, stream>>>(x, l1h, att_q1, xh, sa, src, dst,
                                          cur, csr_src, n, 256, MB, E);
    // ---- layer 1 edge phase (1 wave / node) ----
    fused_edge_k<32, true><<<n, dim3(64), 0, stream>>>(ro, csr_src, xh, sa, att_v1, bias1, acc16, n);
    // ---- layer 2 ----
    gemm2_k<<<MB, blk, 0, stream>>>(acc16, l2h, att_q2, xh, sa, n, 128);
    fused_edge_k<40, false><<<n, dim3(64), 0, stream>>>(ro, csr_src, xh, sa, att_v2, bias2, outp, n);
}

// Round 20
// 290.969 us; speedup vs baseline: 1.1248x; 1.0099x over previous
//
#include <hip/hip_runtime.h>
#include <hip/hip_fp16.h>

#define HEADS 4

typedef _Float16 v2h __attribute__((ext_vector_type(2)));

// load 4 consecutive halfs (8B aligned) -> float4
__device__ __forceinline__ float4 ldh4(const __half* p) {
    const uint2 u = *(const uint2*)p;
    const float2 a = __half22float2(*(const __half2*)&u.x);
    const float2 b = __half22float2(*(const __half2*)&u.y);
    return make_float4(a.x, a.y, b.x, b.y);
}

__device__ __forceinline__ __half2 habs2_(__half2 x) {
    unsigned u = *reinterpret_cast<unsigned*>(&x) & 0x7FFF7FFFu;
    return *reinterpret_cast<__half2*>(&u);
}

__device__ __forceinline__ float fdot2_(__half2 a, __half2 b, float c) {
    return __builtin_amdgcn_fdot2(*(v2h*)&a, *(v2h*)&b, c, false);
}

// ------- wide GEMM + fused alpha: C[M,BN] = A[M,K] @ B[K,BN] -------
// BM=64, BK=32, 256 threads, micro-tile 4 x (BN/16). R15 layout.
// BN=128: B-reads use per-lane index ROTATION (j+tx)&7 -> banks (8tx+(j+tx)%8)
// collide only for tx vs tx+8 = 2-way = free (was 4-way). Same columns per
// lane, just permuted register order; epilogue un-rotates with scalar stores.
template <int BN, bool AHALF>
__device__ __forceinline__ void gemm_alpha_body(
    const void* __restrict__ Av, const __half2* __restrict__ Bh,
    const float* __restrict__ attq, __half* __restrict__ Cout,
    float* __restrict__ sa, int M, int K, int bid) {
    constexpr int BM = 64, BK = 32;
    constexpr int MN = BN / 16;
    constexpr int C = BN / 4;
    constexpr bool ROT = (BN == 128);
    __shared__ v2h As2[BK / 2][BM];
    __shared__ v2h Bs2[BK / 2][BN];
    __shared__ float sred[BM][4];
    __shared__ float aq[BN];
    const int m0 = bid * BM;
    const int tid = threadIdx.x;
    const int ty = tid >> 4;   // 0..15
    const int tx = tid & 15;   // 0..15
    for (int i = tid; i < BN; i += 256) aq[i] = attq[i];
    sred[tid >> 2][tid & 3] = 0.f;   // 256 == BM*4
    float acc[4][MN] = {};

    for (int kt = 0; kt < K; kt += BK) {
        // ---- stage A tile (64 rows x 32 k), k-paired half2, transposed ----
        if (!AHALF) {
            const float* A = (const float*)Av;
            #pragma unroll
            for (int it = 0; it < 2; ++it) {
                const int i = tid + 256 * it;    // 512 float4 slots
                const int row = i >> 3;
                const int kc = (i & 7) * 4;
                const int grow = m0 + row;
                float4 v = make_float4(0.f, 0.f, 0.f, 0.f);
                if (grow < M) v = *(const float4*)&A[(size_t)grow * K + kt + kc];
                v2h p0; p0[0] = (_Float16)v.x; p0[1] = (_Float16)v.y;
                v2h p1; p1[0] = (_Float16)v.z; p1[1] = (_Float16)v.w;
                As2[(kc >> 1) + 0][row] = p0;
                As2[(kc >> 1) + 1][row] = p1;
            }
        } else {
            const __half* A = (const __half*)Av;
            #pragma unroll
            for (int it = 0; it < 2; ++it) {
                const int i = tid + 256 * it;
                const int row = i >> 3;
                const int kc = (i & 7) * 4;
                const int grow = m0 + row;
                uint2 u = make_uint2(0u, 0u);
                if (grow < M) u = *(const uint2*)&A[(size_t)grow * K + kt + kc];
                As2[(kc >> 1) + 0][row] = *(v2h*)&u.x;
                As2[(kc >> 1) + 1][row] = *(v2h*)&u.y;
            }
        }
        // ---- stage B tile (32 k x BN): straight 16B copies (preconverted) --
        {
            constexpr int BCH = (BK / 2) * (BN / 4);  // 16B chunks
            for (int i = tid; i < BCH; i += 256) {
                const int k2 = i / (BN / 4);
                const int n4 = (i % (BN / 4)) * 4;
                *(float4*)&Bs2[k2][n4] =
                    *(const float4*)&Bh[(size_t)(kt / 2 + k2) * BN + n4];
            }
        }
        __syncthreads();
        #pragma unroll
        for (int k2 = 0; k2 < BK / 2; ++k2) {
            v2h a_[4], b_[MN];
            #pragma unroll
            for (int i = 0; i < 4; ++i) a_[i] = As2[k2][ty * 4 + i];
            #pragma unroll
            for (int j = 0; j < MN; ++j)
                b_[j] = Bs2[k2][ROT ? (tx * MN + ((j + tx) & 7))
                                    : (tx * MN + j)];
            #pragma unroll
            for (int i = 0; i < 4; ++i)
                #pragma unroll
                for (int j = 0; j < MN; ++j)
                    acc[i][j] = __builtin_amdgcn_fdot2(a_[i], b_[j], acc[i][j], false);
        }
        __syncthreads();
    }
    // ---- epilogue: fp16 C write + alpha partial reduction ----
    const int cbase = tx * MN;
    const int head = cbase / C;      // MN cols always within one head
    #pragma unroll
    for (int i = 0; i < 4; ++i) {
        const int grow = m0 + ty * 4 + i;
        if (grow < M) {
            float part = 0.f;
            if (ROT) {
                #pragma unroll
                for (int j = 0; j < MN; ++j) {
                    const int col = cbase + ((j + tx) & 7);
                    Cout[(size_t)grow * BN + col] = (__half)acc[i][j];
                    part += acc[i][j] * aq[col];
                }
            } else {
                #pragma unroll
                for (int j = 0; j < MN; j += 2) {
                    const __half2 h = __floats2half2_rn(acc[i][j], acc[i][j + 1]);
                    *(__half2*)&Cout[(size_t)grow * BN + cbase + j] = h;
                }
                #pragma unroll
                for (int j = 0; j < MN; ++j) part += acc[i][j] * aq[cbase + j];
            }
            atomicAdd(&sred[ty * 4 + i][head], part);
        }
    }
    __syncthreads();
    {
        const int row = m0 + (tid >> 2);
        if (row < M)
            sa[row * 4 + (tid & 3)] =
                1.0f / (1.0f + __expf(-sred[tid >> 2][tid & 3]));
    }
}

// ---- prep: weight fp16 k-paired conversion (blocks < CVB) || dst histogram --
__global__ __launch_bounds__(256)
void prep_k(const float* __restrict__ lin1, const float* __restrict__ lin2,
            __half2* __restrict__ l1h, __half2* __restrict__ l2h,
            const int* __restrict__ dst, int* __restrict__ deg,
            int CVB, int E) {
    if ((int)blockIdx.x < CVB) {
        const int t = blockIdx.x * 256 + threadIdx.x;
        if (t < 128 * 128) {
            const int k2 = t >> 7, nn = t & 127;
            l1h[t] = __floats2half2_rn(lin1[(2 * k2) * 128 + nn],
                                       lin1[(2 * k2 + 1) * 128 + nn]);
        } else {
            const int u = t - 128 * 128;
            if (u < 64 * 160) {
                const int k2 = u / 160, nn = u % 160;
                l2h[u] = __floats2half2_rn(lin2[(2 * k2) * 160 + nn],
                                           lin2[(2 * k2 + 1) * 160 + nn]);
            }
        }
    } else {
        const int e = ((int)blockIdx.x - CVB) * 256 + threadIdx.x;
        if (e < E) atomicAdd(&deg[dst[e]], 1);
    }
}

// ---------------- CSR scan ----------------
__global__ __launch_bounds__(256)
void scan1_k(const int* __restrict__ deg, int* __restrict__ ro,
             int* __restrict__ bsum, int n) {
    __shared__ int s[256];
    int i = blockIdx.x * 256 + threadIdx.x;
    int v = (i < n) ? deg[i] : 0;
    s[threadIdx.x] = v;
    __syncthreads();
    for (int off = 1; off < 256; off <<= 1) {
        int t = (threadIdx.x >= off) ? s[threadIdx.x - off] : 0;
        __syncthreads();
        s[threadIdx.x] += t;
        __syncthreads();
    }
    if (i < n) ro[i] = s[threadIdx.x] - v;
    if (threadIdx.x == 255) bsum[blockIdx.x] = s[255];
}

__global__ __launch_bounds__(256)
void scan23_k(int* __restrict__ ro, int* __restrict__ cur,
              const int* __restrict__ bsum, int n, int E, int nb) {
    __shared__ int s[256];
    int v = ((int)threadIdx.x < nb) ? bsum[threadIdx.x] : 0;
    s[threadIdx.x] = v;
    __syncthreads();
    for (int off = 1; off < 256; off <<= 1) {
        int t = (threadIdx.x >= off) ? s[threadIdx.x - off] : 0;
        __syncthreads();
        s[threadIdx.x] += t;
        __syncthreads();
    }
    const int pref = (blockIdx.x == 0) ? 0 : s[blockIdx.x - 1];  // exclusive
    const int i = blockIdx.x * 256 + threadIdx.x;
    if (i < n) {
        const int r = ro[i] + pref;
        ro[i] = r;
        cur[i] = r;
    }
    if (i == 0) ro[n] = E;
}

// ---- front2: layer-1 GEMM+alpha (blocks < MB) || CSR scatter (rest) ----
__global__ __launch_bounds__(256)
void front2_k(const float* __restrict__ x, const __half2* __restrict__ l1h,
              const float* __restrict__ attq1, __half* __restrict__ xh,
              float* __restrict__ sa, const int* __restrict__ src,
              const int* __restrict__ dst, int* __restrict__ cur,
              int* __restrict__ csr_src, int M, int K, int MB, int E) {
    if ((int)blockIdx.x < MB) {
        gemm_alpha_body<128, false>(x, l1h, attq1, xh, sa, M, K, blockIdx.x);
    } else {
        const int e = ((int)blockIdx.x - MB) * 256 + threadIdx.x;
        if (e < E) {
            const int d = dst[e];
            const int pos = atomicAdd(&cur[d], 1);
            csr_src[pos] = src[e];
        }
    }
}

__global__ __launch_bounds__(256)
void gemm2_k(const __half* __restrict__ acc16, const __half2* __restrict__ l2h,
             const float* __restrict__ attq2, __half* __restrict__ xh,
             float* __restrict__ sa, int M, int K) {
    gemm_alpha_body<160, true>(acc16, l2h, attq2, xh, sa, M, K, blockIdx.x);
}

// ---------------- fused logit+softmax+aggregate+epilogue (fp16 xh) ----------
// ONE WAVE PER BLOCK (64 threads), one node per block: measured optimum.
template <int C, bool CONCAT>
__global__ __launch_bounds__(64)
void fused_edge_k(const int* __restrict__ ro, const int* __restrict__ csr_src,
                  const __half* __restrict__ xh, const float* __restrict__ sa,
                  const float* __restrict__ attv, const float* __restrict__ bias,
                  void* __restrict__ outp, int n) {
    constexpr int HC = 4 * C;
    constexpr int QH = C / 4;        // 4-half chunks per head quarter
    constexpr int CHUNK = 64;        // edges per super-chunk
    constexpr bool DUAL = (C <= 32);
    const int lane = threadIdx.x;
    const int node = blockIdx.x;

    __shared__ float wbuf[CHUNK * 4];
    __shared__ int sibuf[CHUNK];
    __shared__ __half2 avs[HC / 2];
    for (int i = lane; i < HC / 2; i += 64)
        avs[i] = __floats2half2_rn(attv[2 * i], attv[2 * i + 1]);
    __syncthreads();
    if (node >= n) return;

    const int s0 = ro[node], s1 = ro[node + 1];

    // logit mapping
    const int e_loc = lane >> 2;
    const int h_l = lane & 3;
    const float sad = sa[node * 4 + h_l];
    const __half2 c505 = __floats2half2_rn(0.505f, 0.505f);
    const __half2 c495 = __floats2half2_rn(0.495f, 0.495f);

    // hoisted dst-row quarter as half2
    __half2 xd[QH * 2];
    {
        const __half* p = &xh[(size_t)node * HC + h_l * C];
        #pragma unroll
        for (int i = 0; i < QH; ++i) {
            const uint2 u = *(const uint2*)&p[i * 4];
            xd[2 * i] = *(const __half2*)&u.x;
            xd[2 * i + 1] = *(const __half2*)&u.y;
        }
    }

    // aggregation mapping
    const int half_ = DUAL ? (lane >> 5) : 0;
    const int q = DUAL ? (lane & 31) : lane;
    const int h_a = (q < C) ? (q / QH) : 0;

    float4 acc = make_float4(0.f, 0.f, 0.f, 0.f);
    float ssum = 0.f;

    for (int base = s0; base < s1; base += CHUNK) {
        const int cnt = min(CHUNK, s1 - base);
        const int npass = (cnt + 15) >> 4;
        // ---- logit passes: 16 edges x 4 heads per pass, packed fp16 ----
        for (int p = 0; p < npass; ++p) {
            const int eidx = p * 16 + e_loc;
            const int j = base + eidx;
            float w = 0.f;
            int si = 0;
            if (j < s1) {
                si = csr_src[j];
                const float sas = sa[si * 4 + h_l];
                const float wa = 1.0f - fabsf(sad - sas);
                const __half* xs = &xh[(size_t)si * HC + h_l * C];
                float wb = 0.f;
                #pragma unroll
                for (int i = 0; i < QH; ++i) {
                    const uint2 u = *(const uint2*)&xs[i * 4];
                    const __half2 a0 = *(const __half2*)&u.x;
                    const __half2 a1 = *(const __half2*)&u.y;
                    const __half2 t0 = __hadd2(a0, xd[2 * i]);
                    const __half2 t1 = __hadd2(a1, xd[2 * i + 1]);
                    const __half2 l0 = __hfma2(t0, c505, __hmul2(habs2_(t0), c495));
                    const __half2 l1 = __hfma2(t1, c505, __hmul2(habs2_(t1), c495));
                    wb = fdot2_(l0, avs[h_l * QH * 2 + 2 * i], wb);
                    wb = fdot2_(l1, avs[h_l * QH * 2 + 2 * i + 1], wb);
                }
                w = __expf(fminf(wa * wb, 60.f));  // inf-guard only
                ssum += w;
            }
            wbuf[eidx * 4 + h_l] = w;
            if (h_l == 0) sibuf[eidx] = si;
        }
        // ---- aggregation: padded slots carry w=0/si=0, no guards ----
        const int padded = npass << 4;
        if (q < C) {
            if (DUAL) {
                for (int i = 0; i < padded; i += 8) {
                    const int e0 = i + half_, e1 = i + half_ + 2;
                    const int e2 = i + half_ + 4, e3 = i + half_ + 6;
                    const int i0 = sibuf[e0], i1 = sibuf[e1];
                    const int i2 = sibuf[e2], i3 = sibuf[e3];
                    const float w0 = wbuf[e0 * 4 + h_a];
                    const float w1 = wbuf[e1 * 4 + h_a];
                    const float w2 = wbuf[e2 * 4 + h_a];
                    const float w3 = wbuf[e3 * 4 + h_a];
                    const float4 v0 = ldh4(&xh[(size_t)i0 * HC + q * 4]);
                    const float4 v1 = ldh4(&xh[(size_t)i1 * HC + q * 4]);
                    const float4 v2 = ldh4(&xh[(size_t)i2 * HC + q * 4]);
                    const float4 v3 = ldh4(&xh[(size_t)i3 * HC + q * 4]);
                    acc.x += w0 * v0.x + w1 * v1.x + w2 * v2.x + w3 * v3.x;
                    acc.y += w0 * v0.y + w1 * v1.y + w2 * v2.y + w3 * v3.y;
                    acc.z += w0 * v0.z + w1 * v1.z + w2 * v2.z + w3 * v3.z;
                    acc.w += w0 * v0.w + w1 * v1.w + w2 * v2.w + w3 * v3.w;
                }
            } else {
                for (int i = 0; i < padded; i += 4) {
                    const int i0 = sibuf[i],     i1 = sibuf[i + 1];
                    const int i2 = sibuf[i + 2], i3 = sibuf[i + 3];
                    const float w0 = wbuf[(i + 0) * 4 + h_a];
                    const float w1 = wbuf[(i + 1) * 4 + h_a];
                    const float w2 = wbuf[(i + 2) * 4 + h_a];
                    const float w3 = wbuf[(i + 3) * 4 + h_a];
                    const float4 v0 = ldh4(&xh[(size_t)i0 * HC + q * 4]);
                    const float4 v1 = ldh4(&xh[(size_t)i1 * HC + q * 4]);
                    const float4 v2 = ldh4(&xh[(size_t)i2 * HC + q * 4]);
                    const float4 v3 = ldh4(&xh[(size_t)i3 * HC + q * 4]);
                    acc.x += w0 * v0.x + w1 * v1.x + w2 * v2.x + w3 * v3.x;
                    acc.y += w0 * v0.y + w1 * v1.y + w2 * v2.y + w3 * v3.y;
                    acc.z += w0 * v0.z + w1 * v1.z + w2 * v2.z + w3 * v3.z;
                    acc.w += w0 * v0.w + w1 * v1.w + w2 * v2.w + w3 * v3.w;
                }
            }
        }
    }

    // combine dual halves
    if (DUAL) {
        acc.x += __shfl_xor(acc.x, 32, 64);
        acc.y += __shfl_xor(acc.y, 32, 64);
        acc.z += __shfl_xor(acc.z, 32, 64);
        acc.w += __shfl_xor(acc.w, 32, 64);
    }

    // per-head sum of weights: reduce across lanes sharing (lane & 3)
    #pragma unroll
    for (int off = 4; off < 64; off <<= 1) ssum += __shfl_xor(ssum, off, 64);
    const float stot = __shfl(ssum, h_a, 64);
    const float inv = 1.0f / (stot + 1e-20f);
    acc.x *= inv; acc.y *= inv; acc.z *= inv; acc.w *= inv;

    if (CONCAT) {
        if (q < C && half_ == 0) {
            const float4 b = ((const float4*)bias)[q];
            float4 v = make_float4(acc.x + b.x, acc.y + b.y, acc.z + b.z, acc.w + b.w);
            v.x = v.x > 0.f ? v.x : __expf(v.x) - 1.0f;
            v.y = v.y > 0.f ? v.y : __expf(v.y) - 1.0f;
            v.z = v.z > 0.f ? v.z : __expf(v.z) - 1.0f;
            v.w = v.w > 0.f ? v.w : __expf(v.w) - 1.0f;
            __half* o16 = (__half*)outp;
            const __half2 h01 = __floats2half2_rn(v.x, v.y);
            const __half2 h23 = __floats2half2_rn(v.z, v.w);
            uint2 u;
            u.x = *(const unsigned*)&h01;
            u.y = *(const unsigned*)&h23;
            *(uint2*)&o16[(size_t)node * HC + q * 4] = u;
        }
    } else {
        // head-mean via shuffles
        const int qq = (q < QH) ? q : 0;
        const float x1 = __shfl(acc.x, qq + QH, 64);
        const float y1 = __shfl(acc.y, qq + QH, 64);
        const float z1 = __shfl(acc.z, qq + QH, 64);
        const float w1 = __shfl(acc.w, qq + QH, 64);
        const float x2 = __shfl(acc.x, qq + 2 * QH, 64);
        const float y2 = __shfl(acc.y, qq + 2 * QH, 64);
        const float z2 = __shfl(acc.z, qq + 2 * QH, 64);
        const float w2 = __shfl(acc.w, qq + 2 * QH, 64);
        const float x3 = __shfl(acc.x, qq + 3 * QH, 64);
        const float y3 = __shfl(acc.y, qq + 3 * QH, 64);
        const float z3 = __shfl(acc.z, qq + 3 * QH, 64);
        const float w3 = __shfl(acc.w, qq + 3 * QH, 64);
        if (q < QH && half_ == 0) {
            float* of = (float*)outp;
            const float4 b = ((const float4*)bias)[q];
            float4 v;
            v.x = 0.25f * (acc.x + x1 + x2 + x3) + b.x;
            v.y = 0.25f * (acc.y + y1 + y2 + y3) + b.y;
            v.z = 0.25f * (acc.z + z1 + z2 + z3) + b.z;
            v.w = 0.25f * (acc.w + w1 + w2 + w3) + b.w;
            *(float4*)&of[(size_t)node * C + q * 4] = v;
        }
    }
}

extern "C" void kernel_launch(void* const* d_in, const int* in_sizes, int n_in,
                              void* d_out, int out_size, void* d_ws, size_t ws_size,
                              hipStream_t stream) {
    const float* x      = (const float*)d_in[0];
    const int*   src    = (const int*)d_in[1];
    const int*   dst    = (const int*)d_in[2];
    const float* lin1   = (const float*)d_in[3];
    const float* att_q1 = (const float*)d_in[4];
    const float* att_v1 = (const float*)d_in[5];
    const float* bias1  = (const float*)d_in[6];
    const float* lin2   = (const float*)d_in[7];
    const float* att_q2 = (const float*)d_in[8];
    const float* att_v2 = (const float*)d_in[9];
    const float* bias2  = (const float*)d_in[10];
    float* outp = (float*)d_out;

    const int n = in_sizes[0] / 256;
    const int E = in_sizes[1];
    const int nh = n * HEADS;
    const int NB = (n + 255) / 256;

    char* wsb = (char*)d_ws;
    size_t o = 0;
    __half* xh     = (__half*)(wsb + o); o += (size_t)n * 160 * 2;
    __half* acc16  = (__half*)(wsb + o); o += (size_t)n * 128 * 2;
    float* sa      = (float*)(wsb + o); o += (size_t)nh * 4;
    int* csr_src   = (int*)(wsb + o); o += (size_t)E * 4;
    int* deg       = (int*)(wsb + o); o += (size_t)n * 4;
    int* ro        = (int*)(wsb + o); o += (size_t)(n + 1) * 4;
    int* cur       = (int*)(wsb + o); o += (size_t)n * 4;
    int* bsum      = (int*)(wsb + o); o += 256 * 4;
    __half2* l1h   = (__half2*)(wsb + o); o += (size_t)128 * 128 * 4;
    __half2* l2h   = (__half2*)(wsb + o); o += (size_t)64 * 160 * 4;

    dim3 blk(256);
    const int EG = (E + 255) / 256;
    const int MB = (n + 63) / 64;
    const int CVB = (128 * 128 + 64 * 160 + 255) / 256;

    // ---- prep: weight conversion || dst histogram ----
    hipMemsetAsync(deg, 0, (size_t)n * 4, stream);
    prep_k<<<CVB + EG, blk, 0, stream>>>(lin1, lin2, l1h, l2h, dst, deg, CVB, E);
    // ---- CSR scan (2 kernels) ----
    scan1_k<<<NB, blk, 0, stream>>>(deg, ro, bsum, n);
    scan23_k<<<NB, blk, 0, stream>>>(ro, cur, bsum, n, E, NB);
    // ---- front2: layer-1 GEMM+alpha || CSR scatter ----
    front2_k<<<MB + EG, blk, 0, stream>>>(x, l1h, att_q1, xh, sa, src, dst,
                                          cur, csr_src, n, 256, MB, E);
    // ---- layer 1 edge phase (1 wave / node) ----
    fused_edge_k<32, true><<<n, dim3(64), 0, stream>>>(ro, csr_src, xh, sa, att_v1, bias1, acc16, n);
    // ---- layer 2 ----
    gemm2_k<<<MB, blk, 0, stream>>>(acc16, l2h, att_q2, xh, sa, n, 128);
    fused_edge_k<40, false><<<n, dim3(64), 0, stream>>>(ro, csr_src, xh, sa, att_v2, bias2, outp, n);
}